// Round 7
// baseline (391.101 us; speedup 1.0000x reference)
//
#include <hip/hip_runtime.h>
#include <hip/hip_bf16.h>
#include <math.h>

typedef __attribute__((ext_vector_type(8))) short short8;
typedef __attribute__((ext_vector_type(4))) float f32x4;

#define NTOK 2048
#define HID  2880
#define QKVD 5120
#define KOFF 4096
#define VOFF 4608
#define ATTD 4096   // N_HEADS*HEAD_DIM

__device__ __forceinline__ unsigned short f2bf(float f) {
  union { float f; unsigned int u; } v; v.f = f;
  unsigned int u = v.u;
  unsigned int r = (u + 0x7FFFu + ((u >> 16) & 1u)) >> 16;
  return (unsigned short)r;
}
__device__ __forceinline__ float bf2f(unsigned short h) {
  union { unsigned int u; float f; } v; v.u = ((unsigned int)h) << 16; return v.f;
}
__device__ __forceinline__ void gload_lds16(const unsigned short* g, unsigned short* l) {
  __builtin_amdgcn_global_load_lds(
      (const __attribute__((address_space(1))) unsigned int*)g,
      (__attribute__((address_space(3))) unsigned int*)l, 16, 0, 0);
}

// ---------------- RoPE cos/sin table (YaRN) ----------------
__global__ void rope_table_kernel(float* __restrict__ ctab, float* __restrict__ stab) {
  int idx = blockIdx.x * 256 + threadIdx.x;
  if (idx >= NTOK * 32) return;
  int pos = idx >> 5, i = idx & 31;
  const double theta = 150000.0;
  const double two_pi = 6.283185307179586476925286766559;
  double freq = pow(theta, (double)i / 32.0);
  double interp = 1.0 / (32.0 * freq);
  double extrap = 1.0 / freq;
  double low  = 32.0 * log(4096.0 / (32.0 * two_pi)) / log(theta);
  double high = 32.0 * log(4096.0 / (1.0  * two_pi)) / log(theta);
  double ramp = ((double)i - low) / (high - low);
  ramp = ramp < 0.0 ? 0.0 : (ramp > 1.0 ? 1.0 : ramp);
  double maskv = 1.0 - ramp;
  double inv = interp * (1.0 - maskv) + extrap * maskv;
  double ang = (double)pos * inv;
  double conc = 0.1 * log(32.0) + 1.0;
  ctab[idx] = (float)(cos(ang) * conc);
  stab[idx] = (float)(sin(ang) * conc);
}

// ---------------- RMSNorm fp32 -> bf16 (vectorized) ----------------
__global__ __launch_bounds__(256) void rmsnorm_kernel(
    const float* __restrict__ x, const float* __restrict__ scale,
    unsigned short* __restrict__ t) {
  int row = blockIdx.x;
  const float4* xr = (const float4*)(x + (size_t)row * HID);
  const float4* sc = (const float4*)scale;
  float ss = 0.f;
  for (int c = threadIdx.x; c < HID / 4; c += 256) {
    float4 v = xr[c];
    ss += v.x * v.x + v.y * v.y + v.z * v.z + v.w * v.w;
  }
  #pragma unroll
  for (int m = 1; m < 64; m <<= 1) ss += __shfl_xor(ss, m);
  __shared__ float red[4];
  if ((threadIdx.x & 63) == 0) red[threadIdx.x >> 6] = ss;
  __syncthreads();
  float tot = red[0] + red[1] + red[2] + red[3];
  float rs = rsqrtf(tot / (float)HID + 1e-5f);
  for (int c = threadIdx.x; c < HID / 4; c += 256) {
    float4 v = xr[c];
    float4 s4 = sc[c];
    ushort4 o;
    o.x = f2bf(v.x * rs * s4.x); o.y = f2bf(v.y * rs * s4.y);
    o.z = f2bf(v.z * rs * s4.z); o.w = f2bf(v.w * rs * s4.w);
    *(ushort4*)&t[(size_t)row * HID + c * 4] = o;
  }
}

// ---------------- Weight fp32 -> bf16 ----------------
__global__ __launch_bounds__(256) void cvt_w_kernel(
    const float* __restrict__ w, unsigned short* __restrict__ wb, long total4) {
  long idx = (long)blockIdx.x * 256 + threadIdx.x;
  if (idx >= total4) return;
  long base = idx * 4;
  float4 v = *(const float4*)&w[base];
  ushort4 o;
  o.x = f2bf(v.x); o.y = f2bf(v.y); o.z = f2bf(v.z); o.w = f2bf(v.w);
  *(ushort4*)&wb[base] = o;
}

// ---------------- Pipelined GEMM: B via LDS (swizzled), A direct global->VGPR ----
// C[M,NC] = A[M,K]bf16 @ B[NC,K]bf16^T (+bias, +resid)
// BM=128, BN in {320,192}; BK=64; 512 thr = 8 waves (2M x 4N); dbuf B-LDS,
// per tile: [8 A-loads(t)] [stage B(t+1)] vmcnt(NB) barrier ds_read+MFMA barrier.
template<int BN, bool RESID>
__global__ __launch_bounds__(512, 2) void gemm8p_kernel(
    const unsigned short* __restrict__ A, const unsigned short* __restrict__ B,
    const float* __restrict__ bias, const float* __restrict__ resid,
    void* __restrict__ Cout, int K, int NC) {
  constexpr int NF = BN / 64;         // N-frags per wave (5 or 3)
  constexpr int NB = BN / 64;         // B slices (64 rows each)
  __shared__ unsigned short sB[2][BN * 64];

  const int tid = threadIdx.x;
  // XCD-aware swizzle (grid % 8 == 0 for both launches)
  const int q8 = gridDim.x >> 3;
  const int sw = ((int)blockIdx.x & 7) * q8 + ((int)blockIdx.x >> 3);
  const int m0 = (sw & 15) * 128;
  const int n0 = (sw >> 4) * BN;

  const int lane = tid & 63, wid = tid >> 6;
  const int fr = lane & 15, fq = lane >> 4;
  const int wr = wid >> 2, wc = wid & 3;
  const int swz = (fr & 7) << 4;                     // read-side XOR (byte bits 4,5,6)
  const int r_st = tid >> 3;                         // staged row within 64-row slice
  const int c8_st = ((tid & 7) ^ ((tid >> 3) & 7)) * 8;  // inverse-swizzled source chunk
  const int wlds = wid << 9;                         // wave's 1KB chunk (ushort units)

  const unsigned short* Bg = B + (size_t)(n0 + r_st) * K + c8_st;
  // per-lane A row pointers (loop-invariant): lane (fr,fq) of wave (wr)
  const unsigned short* pA0 = A + (size_t)(m0 + wr * 64 +  0 + fr) * K + fq * 8;
  const unsigned short* pA1 = A + (size_t)(m0 + wr * 64 + 16 + fr) * K + fq * 8;
  const unsigned short* pA2 = A + (size_t)(m0 + wr * 64 + 32 + fr) * K + fq * 8;
  const unsigned short* pA3 = A + (size_t)(m0 + wr * 64 + 48 + fr) * K + fq * 8;

  f32x4 acc[4][NF] = {};
  const int NT = K >> 6;

  auto LDB_ = [&](int bs, int nf, int ks) -> short8 {
    int row = wc * (NF * 16) + nf * 16 + fr;         // row&7 == fr&7
    int cb = (ks * 64 + fq * 16) ^ swz;
    return *(const short8*)((const char*)&sB[bs][0] + row * 128 + cb);
  };
  auto issue_tileB = [&](int tt, int b) {
    const unsigned short* Bgt = Bg + (size_t)tt * 64;
    #pragma unroll
    for (int s = 0; s < NB; ++s)
      gload_lds16(Bgt + (size_t)(s * 64) * K, &sB[b][s * 4096 + wlds]);
  };

  // -------- prologue: issue tile 0's B into buf 0 (no wait yet)
  issue_tileB(0, 0);

  for (int t = 0; t < NT; ++t) {
    const int cu = t & 1;
    const int ko = t * 64;
    // ---- A fragments for tile t: direct global->VGPR (8 x dwordx4)
    short8 a00 = *(const short8*)(pA0 + ko);
    short8 a01 = *(const short8*)(pA1 + ko);
    short8 a02 = *(const short8*)(pA2 + ko);
    short8 a03 = *(const short8*)(pA3 + ko);
    short8 a10 = *(const short8*)(pA0 + ko + 32);
    short8 a11 = *(const short8*)(pA1 + ko + 32);
    short8 a12 = *(const short8*)(pA2 + ko + 32);
    short8 a13 = *(const short8*)(pA3 + ko + 32);
    // ---- stage B(t+1), then ONE counted wait: completes A(t)+B(t),
    //      leaves B(t+1)'s NB loads in flight.
    if (t + 1 < NT) {
      issue_tileB(t + 1, cu ^ 1);
      if constexpr (NB == 5) asm volatile("s_waitcnt vmcnt(5)" ::: "memory");
      else                   asm volatile("s_waitcnt vmcnt(3)" ::: "memory");
    } else {
      asm volatile("s_waitcnt vmcnt(0)" ::: "memory");
    }
    __builtin_amdgcn_s_barrier();          // buf cu ready for all waves
    __builtin_amdgcn_sched_barrier(0);     // keep ds_reads below readiness point
    // ---- compute on buf cu (B from LDS, A already in VGPRs)
    {
      short8 bfr[NF];
      #pragma unroll
      for (int nf = 0; nf < NF; ++nf) bfr[nf] = LDB_(cu, nf, 0);
      __builtin_amdgcn_s_setprio(1);
      #pragma unroll
      for (int nf = 0; nf < NF; ++nf) {
        acc[0][nf] = __builtin_amdgcn_mfma_f32_16x16x32_bf16(a00, bfr[nf], acc[0][nf], 0, 0, 0);
        acc[1][nf] = __builtin_amdgcn_mfma_f32_16x16x32_bf16(a01, bfr[nf], acc[1][nf], 0, 0, 0);
        acc[2][nf] = __builtin_amdgcn_mfma_f32_16x16x32_bf16(a02, bfr[nf], acc[2][nf], 0, 0, 0);
        acc[3][nf] = __builtin_amdgcn_mfma_f32_16x16x32_bf16(a03, bfr[nf], acc[3][nf], 0, 0, 0);
      }
      __builtin_amdgcn_s_setprio(0);
    }
    {
      short8 bfr[NF];
      #pragma unroll
      for (int nf = 0; nf < NF; ++nf) bfr[nf] = LDB_(cu, nf, 1);
      __builtin_amdgcn_s_setprio(1);
      #pragma unroll
      for (int nf = 0; nf < NF; ++nf) {
        acc[0][nf] = __builtin_amdgcn_mfma_f32_16x16x32_bf16(a10, bfr[nf], acc[0][nf], 0, 0, 0);
        acc[1][nf] = __builtin_amdgcn_mfma_f32_16x16x32_bf16(a11, bfr[nf], acc[1][nf], 0, 0, 0);
        acc[2][nf] = __builtin_amdgcn_mfma_f32_16x16x32_bf16(a12, bfr[nf], acc[2][nf], 0, 0, 0);
        acc[3][nf] = __builtin_amdgcn_mfma_f32_16x16x32_bf16(a13, bfr[nf], acc[3][nf], 0, 0, 0);
      }
      __builtin_amdgcn_s_setprio(0);
    }
    // ---- end of tile: reads from buf cu done -> next iter may stage into it
    __builtin_amdgcn_s_barrier();
  }

  // -------- epilogue
  if (!RESID) {
    unsigned short* C = (unsigned short*)Cout;
    #pragma unroll
    for (int mf = 0; mf < 4; ++mf)
      #pragma unroll
      for (int nf = 0; nf < NF; ++nf)
        #pragma unroll
        for (int r = 0; r < 4; ++r) {
          int row = m0 + wr * 64 + mf * 16 + fq * 4 + r;
          int col = n0 + wc * (NF * 16) + nf * 16 + fr;
          C[(size_t)row * NC + col] = f2bf(acc[mf][nf][r] + bias[col]);
        }
  } else {
    float* C = (float*)Cout;
    #pragma unroll
    for (int mf = 0; mf < 4; ++mf)
      #pragma unroll
      for (int nf = 0; nf < NF; ++nf)
        #pragma unroll
        for (int r = 0; r < 4; ++r) {
          int row = m0 + wr * 64 + mf * 16 + fq * 4 + r;
          int col = n0 + wc * (NF * 16) + nf * 16 + fr;
          C[(size_t)row * NC + col] = acc[mf][nf][r] + bias[col] + resid[(size_t)row * NC + col];
        }
  }
}

// ---------------- MFMA sliding-window attention with sinks + fused RoPE ----------------
__global__ __launch_bounds__(256) void attn_kernel(
    const unsigned short* __restrict__ qkv, const float* __restrict__ sinks,
    const float* __restrict__ ctab, const float* __restrict__ stab,
    unsigned short* __restrict__ attn) {
  const int tile = blockIdx.x;
  const int gh = blockIdx.y;
  const int h = gh >> 3;
  const int q0 = tile * 64;
  const int kbase = q0 - 127;

  __shared__ unsigned short Qsh[64][72];
  __shared__ unsigned short Ksh[192][72];
  __shared__ unsigned short Vt[64][200];    // transposed V: [dim][key]
  __shared__ float rowpart[4][64];
  __shared__ float invsum[64];
  unsigned short (*Wsh)[200] = (unsigned short (*)[200])Ksh;  // overlay after scores

  const int tid = threadIdx.x;

  // ---- stage Q with RoPE: thread = (row, chunk-pair)
  {
    int r = tid >> 2, cp = tid & 3;
    int i = q0 + r;
    const unsigned short* qp = &qkv[(size_t)i * QKVD + gh * 64 + cp * 8];
    short8 xa = *(const short8*)qp;
    short8 xb = *(const short8*)(qp + 32);
    short8 oa, ob;
    #pragma unroll
    for (int e = 0; e < 8; ++e) {
      float c = ctab[i * 32 + cp * 8 + e], s = stab[i * 32 + cp * 8 + e];
      float x1 = bf2f((unsigned short)xa[e]), x2 = bf2f((unsigned short)xb[e]);
      oa[e] = (short)f2bf(x1 * c - x2 * s);
      ob[e] = (short)f2bf(x2 * c + x1 * s);
    }
    *(short8*)&Qsh[r][cp * 8] = oa;
    *(short8*)&Qsh[r][cp * 8 + 32] = ob;
  }
  // ---- stage K with RoPE, zero-fill out-of-range
  #pragma unroll
  for (int it = 0; it < 3; ++it) {
    int lin = tid + it * 256;
    int r = lin >> 2, cp = lin & 3;
    int j = kbase + r;
    short8 oa = {}, ob = {};
    if (j >= 0 && j < NTOK) {
      const unsigned short* kp = &qkv[(size_t)j * QKVD + KOFF + h * 64 + cp * 8];
      short8 xa = *(const short8*)kp;
      short8 xb = *(const short8*)(kp + 32);
      #pragma unroll
      for (int e = 0; e < 8; ++e) {
        float c = ctab[j * 32 + cp * 8 + e], s = stab[j * 32 + cp * 8 + e];
        float x1 = bf2f((unsigned short)xa[e]), x2 = bf2f((unsigned short)xb[e]);
        oa[e] = (short)f2bf(x1 * c - x2 * s);
        ob[e] = (short)f2bf(x2 * c + x1 * s);
      }
    }
    *(short8*)&Ksh[r][cp * 8] = oa;
    *(short8*)&Ksh[r][cp * 8 + 32] = ob;
  }
  // ---- stage V transposed
  #pragma unroll
  for (int c = 0; c < 6; ++c) {
    int lin = tid + c * 256;
    int r = lin >> 3, ch = (lin & 7) * 8;
    int j = kbase + r;
    uint4 v = make_uint4(0u, 0u, 0u, 0u);
    if (j >= 0 && j < NTOK) v = *(const uint4*)&qkv[(size_t)j * QKVD + VOFF + h * 64 + ch];
    const unsigned short* vs = (const unsigned short*)&v;
    #pragma unroll
    for (int i2 = 0; i2 < 8; ++i2) Vt[ch + i2][r] = vs[i2];
  }
  __syncthreads();

  const int lane = tid & 63;
  const int wid = tid >> 6;
  const int fr = lane & 15;
  const int fq = lane >> 4;
  const int fc = fq * 8;
  const int wk0 = wid * 48;     // this wave's 48-key range

  // ---- scores: S[64][48] per wave
  f32x4 sc[4][3] = {};
  #pragma unroll
  for (int k0 = 0; k0 < 64; k0 += 32) {
    short8 qa[4], kb[3];
    #pragma unroll
    for (int mi = 0; mi < 4; ++mi) qa[mi] = *(const short8*)&Qsh[mi * 16 + fr][k0 + fc];
    #pragma unroll
    for (int ni = 0; ni < 3; ++ni) kb[ni] = *(const short8*)&Ksh[wk0 + ni * 16 + fr][k0 + fc];
    #pragma unroll
    for (int mi = 0; mi < 4; ++mi)
      #pragma unroll
      for (int ni = 0; ni < 3; ++ni)
        sc[mi][ni] = __builtin_amdgcn_mfma_f32_16x16x32_bf16(qa[mi], kb[ni], sc[mi][ni], 0, 0, 0);
  }

  // ---- mask + exp in-register; per-row partial sums
  float rsum[4][4];
  #pragma unroll
  for (int mi = 0; mi < 4; ++mi)
    #pragma unroll
    for (int r = 0; r < 4; ++r) {
      int i = q0 + mi * 16 + fq * 4 + r;
      float rs = 0.f;
      #pragma unroll
      for (int ni = 0; ni < 3; ++ni) {
        int kk = wk0 + ni * 16 + fr;
        int j = kbase + kk;
        bool valid = (j >= 0) && (j <= i) && (j > i - 128);
        float pw = valid ? __expf(sc[mi][ni][r] * 0.125f) : 0.f;
        sc[mi][ni][r] = pw;
        rs += pw;
      }
      rs += __shfl_xor(rs, 1);
      rs += __shfl_xor(rs, 2);
      rs += __shfl_xor(rs, 4);
      rs += __shfl_xor(rs, 8);
      rsum[mi][r] = rs;
    }

  __syncthreads();   // all Ksh reads complete; safe to overlay Wsh

  #pragma unroll
  for (int mi = 0; mi < 4; ++mi)
    #pragma unroll
    for (int r = 0; r < 4; ++r) {
      int row = mi * 16 + fq * 4 + r;
      #pragma unroll
      for (int ni = 0; ni < 3; ++ni)
        Wsh[row][wk0 + ni * 16 + fr] = f2bf(sc[mi][ni][r]);
      if (fr == 0) rowpart[wid][row] = rsum[mi][r];
    }
  __syncthreads();

  if (tid < 64) {
    float tot = rowpart[0][tid] + rowpart[1][tid] + rowpart[2][tid] + rowpart[3][tid];
    invsum[tid] = 1.f / (tot + __expf(sinks[gh]));
  }

  // ---- PV: out[64][16] per wave, K=192
  f32x4 pv[4] = {};
  #pragma unroll
  for (int k0 = 0; k0 < 192; k0 += 32) {
    short8 pa[4];
    #pragma unroll
    for (int mi = 0; mi < 4; ++mi) pa[mi] = *(const short8*)&Wsh[mi * 16 + fr][k0 + fc];
    short8 vb = *(const short8*)&Vt[wid * 16 + fr][k0 + fc];
    #pragma unroll
    for (int mi = 0; mi < 4; ++mi)
      pv[mi] = __builtin_amdgcn_mfma_f32_16x16x32_bf16(pa[mi], vb, pv[mi], 0, 0, 0);
  }
  __syncthreads();   // invsum visible

  #pragma unroll
  for (int mi = 0; mi < 4; ++mi)
    #pragma unroll
    for (int r = 0; r < 4; ++r) {
      int row = mi * 16 + fq * 4 + r;
      float inv = invsum[row];
      int col = wid * 16 + fr;
      attn[(size_t)(q0 + row) * ATTD + gh * 64 + col] = f2bf(pv[mi][r] * inv);
    }
}

extern "C" void kernel_launch(void* const* d_in, const int* in_sizes, int n_in,
                              void* d_out, int out_size, void* d_ws, size_t ws_size,
                              hipStream_t stream) {
  const float* x          = (const float*)d_in[0];
  const float* norm_scale = (const float*)d_in[1];
  const float* sinks      = (const float*)d_in[2];
  const float* w_qkv      = (const float*)d_in[3];
  const float* b_qkv      = (const float*)d_in[4];
  const float* w_out      = (const float*)d_in[5];
  const float* b_out      = (const float*)d_in[6];
  float* out = (float*)d_out;

  // workspace:
  //   [0, 21.0MB)     qkv_bf  (2048x5120 bf16, pre-RoPE)
  //   [21.0, 37.8MB)  t_bf (11.8MB, dead after gemm1) overlaid by attn_b (16.8MB)
  //   [37.8, 67.3MB)  wbf (w_qkv_bf 29.5MB, then w_out_bf 23.6MB)
  //   [67.3, 67.9MB)  ctab, stab
  char* ws = (char*)d_ws;
  unsigned short* qkv_bf = (unsigned short*)(ws);
  unsigned short* t_bf   = (unsigned short*)(ws + 20971520);
  unsigned short* attn_b = (unsigned short*)(ws + 20971520);
  unsigned short* wbf    = (unsigned short*)(ws + 20971520 + 16777216);
  float*          ctab   = (float*)(ws + 20971520 + 16777216 + 29491200);
  float*          stab   = ctab + NTOK * 32;

  rope_table_kernel<<<dim3(256), dim3(256), 0, stream>>>(ctab, stab);
  rmsnorm_kernel<<<dim3(NTOK), dim3(256), 0, stream>>>(x, norm_scale, t_bf);
  // w_qkv: 5120x2880 fp32 -> bf16
  cvt_w_kernel<<<dim3(14400), dim3(256), 0, stream>>>(w_qkv, wbf, 3686400L);
  // GEMM1: 2048x5120x2880, tiles 128x320 -> 16x16 = 256 blocks
  gemm8p_kernel<320, false><<<dim3(256), dim3(512), 0, stream>>>(
      t_bf, wbf, b_qkv, nullptr, (void*)qkv_bf, HID, QKVD);
  attn_kernel<<<dim3(32, 64), dim3(256), 0, stream>>>(qkv_bf, sinks, ctab, stab, attn_b);
  // w_out: 2880x4096 fp32 -> bf16
  cvt_w_kernel<<<dim3(11520), dim3(256), 0, stream>>>(w_out, wbf, 2949120L);
  // GEMM2: 2048x2880x4096, tiles 128x192 -> 16x15 = 240 blocks
  gemm8p_kernel<192, true><<<dim3(240), dim3(512), 0, stream>>>(
      attn_b, wbf, b_out, x, (void*)out, ATTD, HID);
}

// Round 8
// 268.360 us; speedup vs baseline: 1.4574x; 1.4574x over previous
//
#include <hip/hip_runtime.h>
#include <hip/hip_bf16.h>
#include <math.h>

typedef __attribute__((ext_vector_type(8))) short short8;
typedef __attribute__((ext_vector_type(4))) float f32x4;

#define NTOK 2048
#define HID  2880
#define QKVD 5120
#define KOFF 4096
#define VOFF 4608
#define ATTD 4096   // N_HEADS*HEAD_DIM

__device__ __forceinline__ unsigned short f2bf(float f) {
  union { float f; unsigned int u; } v; v.f = f;
  unsigned int u = v.u;
  unsigned int r = (u + 0x7FFFu + ((u >> 16) & 1u)) >> 16;
  return (unsigned short)r;
}
__device__ __forceinline__ float bf2f(unsigned short h) {
  union { unsigned int u; float f; } v; v.u = ((unsigned int)h) << 16; return v.f;
}
__device__ __forceinline__ void gload_lds16(const unsigned short* g, unsigned short* l) {
  __builtin_amdgcn_global_load_lds(
      (const __attribute__((address_space(1))) unsigned int*)g,
      (__attribute__((address_space(3))) unsigned int*)l, 16, 0, 0);
}
#define MFMA16(a, b, c) __builtin_amdgcn_mfma_f32_16x16x32_bf16((a), (b), (c), 0, 0, 0)

// ---------------- RoPE cos/sin table (YaRN) ----------------
__global__ void rope_table_kernel(float* __restrict__ ctab, float* __restrict__ stab) {
  int idx = blockIdx.x * 256 + threadIdx.x;
  if (idx >= NTOK * 32) return;
  int pos = idx >> 5, i = idx & 31;
  const double theta = 150000.0;
  const double two_pi = 6.283185307179586476925286766559;
  double freq = pow(theta, (double)i / 32.0);
  double interp = 1.0 / (32.0 * freq);
  double extrap = 1.0 / freq;
  double low  = 32.0 * log(4096.0 / (32.0 * two_pi)) / log(theta);
  double high = 32.0 * log(4096.0 / (1.0  * two_pi)) / log(theta);
  double ramp = ((double)i - low) / (high - low);
  ramp = ramp < 0.0 ? 0.0 : (ramp > 1.0 ? 1.0 : ramp);
  double maskv = 1.0 - ramp;
  double inv = interp * (1.0 - maskv) + extrap * maskv;
  double ang = (double)pos * inv;
  double conc = 0.1 * log(32.0) + 1.0;
  ctab[idx] = (float)(cos(ang) * conc);
  stab[idx] = (float)(sin(ang) * conc);
}

// ---------------- RMSNorm fp32 -> bf16 (vectorized) ----------------
__global__ __launch_bounds__(256) void rmsnorm_kernel(
    const float* __restrict__ x, const float* __restrict__ scale,
    unsigned short* __restrict__ t) {
  int row = blockIdx.x;
  const float4* xr = (const float4*)(x + (size_t)row * HID);
  const float4* sc = (const float4*)scale;
  float ss = 0.f;
  for (int c = threadIdx.x; c < HID / 4; c += 256) {
    float4 v = xr[c];
    ss += v.x * v.x + v.y * v.y + v.z * v.z + v.w * v.w;
  }
  #pragma unroll
  for (int m = 1; m < 64; m <<= 1) ss += __shfl_xor(ss, m);
  __shared__ float red[4];
  if ((threadIdx.x & 63) == 0) red[threadIdx.x >> 6] = ss;
  __syncthreads();
  float tot = red[0] + red[1] + red[2] + red[3];
  float rs = rsqrtf(tot / (float)HID + 1e-5f);
  for (int c = threadIdx.x; c < HID / 4; c += 256) {
    float4 v = xr[c];
    float4 s4 = sc[c];
    ushort4 o;
    o.x = f2bf(v.x * rs * s4.x); o.y = f2bf(v.y * rs * s4.y);
    o.z = f2bf(v.z * rs * s4.z); o.w = f2bf(v.w * rs * s4.w);
    *(ushort4*)&t[(size_t)row * HID + c * 4] = o;
  }
}

// ---------------- Weight fp32 -> bf16 ----------------
__global__ __launch_bounds__(256) void cvt_w_kernel(
    const float* __restrict__ w, unsigned short* __restrict__ wb, long total4) {
  long idx = (long)blockIdx.x * 256 + threadIdx.x;
  if (idx >= total4) return;
  long base = idx * 4;
  float4 v = *(const float4*)&w[base];
  ushort4 o;
  o.x = f2bf(v.x); o.y = f2bf(v.y); o.z = f2bf(v.z); o.w = f2bf(v.w);
  *(ushort4*)&wb[base] = o;
}

// ---------------- 4-phase slice-gated pipelined GEMM ----------------
// C[M,NC] = A[M,K]bf16 @ B[NC,K]bf16^T (+bias, +resid)
// BM=128, BN in {320,192}; BK=64; 512 thr = 8 waves (2M x 4N).
// Wave's B cols INTERLEAVED: frag nf covers B rows nf*64 + wc*16 + fr, so
// phase j's B-frag group maps exactly to staged B-slices (slice gating).
// Per K-tile: 4 phases {P0: mf01 x nfL, P1: mf01 x nfH, P2: mf23 x nfL,
// P3: mf23 x nfH}; t+1 staging spread A0A1@P0, B01@P1, B23@P2, B4@P3;
// counted vmcnt(2) at P0/P1 only (slice-complete, >=2-phase slack, never 0).
template<int BN, bool RESID>
__global__ __launch_bounds__(512, 2) void gemm4p_kernel(
    const unsigned short* __restrict__ A, const unsigned short* __restrict__ B,
    const float* __restrict__ bias, const float* __restrict__ resid,
    void* __restrict__ Cout, int K, int NC) {
  constexpr int NF  = BN / 64;            // 5 (GEMM1) or 3 (GEMM2)
  constexpr int NFL = (NF == 5) ? 3 : 1;  // nfL group size
  __shared__ unsigned short sA[2][8192];
  __shared__ unsigned short sB[2][BN * 64];

  const int tid = threadIdx.x;
  const int q8 = gridDim.x >> 3;
  const int sw = ((int)blockIdx.x & 7) * q8 + ((int)blockIdx.x >> 3);
  const int m0 = (sw & 15) * 128;
  const int n0 = (sw >> 4) * BN;

  const int lane = tid & 63, wid = tid >> 6;
  const int fr = lane & 15, fq = lane >> 4;
  const int wr = wid >> 2, wc = wid & 3;
  const int swz = (fr & 7) << 4;
  const int r_st = tid >> 3;
  const int c8_st = ((tid & 7) ^ ((tid >> 3) & 7)) * 8;
  const int wlds = wid << 9;

  const unsigned short* Ag = A + (size_t)(m0 + r_st) * K + c8_st;
  const unsigned short* Bg = B + (size_t)(n0 + r_st) * K + c8_st;

  f32x4 acc[4][NF] = {};
  const int NT = K >> 6;

  auto LDA_ = [&](int bs, int mf, int ks) -> short8 {
    int row = wr * 64 + mf * 16 + fr;                 // row&7 == fr&7
    int cb = (ks * 64 + fq * 16) ^ swz;
    return *(const short8*)((const char*)&sA[bs][0] + row * 128 + cb);
  };
  auto LDB_ = [&](int bs, int nf, int ks) -> short8 {
    int row = nf * 64 + wc * 16 + fr;                 // interleaved cols; row&7==fr&7
    int cb = (ks * 64 + fq * 16) ^ swz;
    return *(const short8*)((const char*)&sB[bs][0] + row * 128 + cb);
  };
  auto stA = [&](int tt, int b, int s) {
    gload_lds16(Ag + (size_t)tt * 64 + (size_t)(s * 64) * K, &sA[b][s * 4096 + wlds]);
  };
  auto stB = [&](int tt, int b, int s) {
    gload_lds16(Bg + (size_t)tt * 64 + (size_t)(s * 64) * K, &sB[b][s * 4096 + wlds]);
  };

  // -------- prologue: issue tile 0 in canonical order A0,A1,B0..B{NF-1}
  stA(0, 0, 0); stA(0, 0, 1);
  #pragma unroll
  for (int s = 0; s < NF; ++s) stB(0, 0, s);

  short8 bk0[NF], bk1[NF];

  for (int t = 0; t < NT; ++t) {
    const int cu = t & 1, nx = cu ^ 1;
    const bool pf = (t + 1 < NT);

    // ================= Phase 0: mf{0,1} x nf[0,NFL) =================
    // need t's A0,A1,B0..B{NFL-1} (oldest 2+NFL of its stream)
    asm volatile("s_waitcnt vmcnt(2)" ::: "memory");
    __builtin_amdgcn_s_barrier();
    __builtin_amdgcn_sched_barrier(0);
    if (pf) { stA(t + 1, nx, 0); stA(t + 1, nx, 1); }
    short8 a00 = LDA_(cu, 0, 0), a01 = LDA_(cu, 0, 1);
    short8 a10 = LDA_(cu, 1, 0), a11 = LDA_(cu, 1, 1);
    #pragma unroll
    for (int nf = 0; nf < NFL; ++nf) { bk0[nf] = LDB_(cu, nf, 0); bk1[nf] = LDB_(cu, nf, 1); }
    __builtin_amdgcn_s_setprio(1);
    #pragma unroll
    for (int nf = 0; nf < NFL; ++nf) {
      acc[0][nf] = MFMA16(a00, bk0[nf], acc[0][nf]);
      acc[0][nf] = MFMA16(a01, bk1[nf], acc[0][nf]);
      acc[1][nf] = MFMA16(a10, bk0[nf], acc[1][nf]);
      acc[1][nf] = MFMA16(a11, bk1[nf], acc[1][nf]);
    }
    __builtin_amdgcn_s_setprio(0);
    __builtin_amdgcn_sched_barrier(0);

    // ================= Phase 1: mf{0,1} x nf[NFL,NF) =================
    // need remainder of t's stream; t+1's A0,A1 stay in flight
    if (pf) asm volatile("s_waitcnt vmcnt(2)" ::: "memory");
    else    asm volatile("s_waitcnt vmcnt(0)" ::: "memory");
    __builtin_amdgcn_s_barrier();
    __builtin_amdgcn_sched_barrier(0);
    if (pf) {
      stB(t + 1, nx, 0);
      if constexpr (NF == 5) stB(t + 1, nx, 1);
    }
    #pragma unroll
    for (int nf = NFL; nf < NF; ++nf) { bk0[nf] = LDB_(cu, nf, 0); bk1[nf] = LDB_(cu, nf, 1); }
    __builtin_amdgcn_s_setprio(1);
    #pragma unroll
    for (int nf = NFL; nf < NF; ++nf) {
      acc[0][nf] = MFMA16(a00, bk0[nf], acc[0][nf]);
      acc[0][nf] = MFMA16(a01, bk1[nf], acc[0][nf]);
      acc[1][nf] = MFMA16(a10, bk0[nf], acc[1][nf]);
      acc[1][nf] = MFMA16(a11, bk1[nf], acc[1][nf]);
    }
    __builtin_amdgcn_s_setprio(0);
    __builtin_amdgcn_sched_barrier(0);

    // ================= Phase 2: mf{2,3} x nf[0,NFL) =================
    __builtin_amdgcn_s_barrier();
    __builtin_amdgcn_sched_barrier(0);
    if (pf) {
      if constexpr (NF == 5) { stB(t + 1, nx, 2); stB(t + 1, nx, 3); }
      else                   { stB(t + 1, nx, 1); }
    }
    short8 a20 = LDA_(cu, 2, 0), a21 = LDA_(cu, 2, 1);
    short8 a30 = LDA_(cu, 3, 0), a31 = LDA_(cu, 3, 1);
    __builtin_amdgcn_s_setprio(1);
    #pragma unroll
    for (int nf = 0; nf < NFL; ++nf) {
      acc[2][nf] = MFMA16(a20, bk0[nf], acc[2][nf]);
      acc[2][nf] = MFMA16(a21, bk1[nf], acc[2][nf]);
      acc[3][nf] = MFMA16(a30, bk0[nf], acc[3][nf]);
      acc[3][nf] = MFMA16(a31, bk1[nf], acc[3][nf]);
    }
    __builtin_amdgcn_s_setprio(0);
    __builtin_amdgcn_sched_barrier(0);

    // ================= Phase 3: mf{2,3} x nf[NFL,NF) =================
    __builtin_amdgcn_s_barrier();
    __builtin_amdgcn_sched_barrier(0);
    if (pf) {
      if constexpr (NF == 5) stB(t + 1, nx, 4);
      else                   stB(t + 1, nx, 2);
    }
    __builtin_amdgcn_s_setprio(1);
    #pragma unroll
    for (int nf = NFL; nf < NF; ++nf) {
      acc[2][nf] = MFMA16(a20, bk0[nf], acc[2][nf]);
      acc[2][nf] = MFMA16(a21, bk1[nf], acc[2][nf]);
      acc[3][nf] = MFMA16(a30, bk0[nf], acc[3][nf]);
      acc[3][nf] = MFMA16(a31, bk1[nf], acc[3][nf]);
    }
    __builtin_amdgcn_s_setprio(0);
    __builtin_amdgcn_sched_barrier(0);
  }

  // -------- epilogue (interleaved col mapping: col = n0 + nf*64 + wc*16 + fr)
  if (!RESID) {
    unsigned short* C = (unsigned short*)Cout;
    #pragma unroll
    for (int mf = 0; mf < 4; ++mf)
      #pragma unroll
      for (int nf = 0; nf < NF; ++nf)
        #pragma unroll
        for (int r = 0; r < 4; ++r) {
          int row = m0 + wr * 64 + mf * 16 + fq * 4 + r;
          int col = n0 + nf * 64 + wc * 16 + fr;
          C[(size_t)row * NC + col] = f2bf(acc[mf][nf][r] + bias[col]);
        }
  } else {
    float* C = (float*)Cout;
    #pragma unroll
    for (int mf = 0; mf < 4; ++mf)
      #pragma unroll
      for (int nf = 0; nf < NF; ++nf)
        #pragma unroll
        for (int r = 0; r < 4; ++r) {
          int row = m0 + wr * 64 + mf * 16 + fq * 4 + r;
          int col = n0 + nf * 64 + wc * 16 + fr;
          C[(size_t)row * NC + col] = acc[mf][nf][r] + bias[col] + resid[(size_t)row * NC + col];
        }
  }
}

// ---------------- MFMA sliding-window attention with sinks + fused RoPE ----------------
__global__ __launch_bounds__(256) void attn_kernel(
    const unsigned short* __restrict__ qkv, const float* __restrict__ sinks,
    const float* __restrict__ ctab, const float* __restrict__ stab,
    unsigned short* __restrict__ attn) {
  const int tile = blockIdx.x;
  const int gh = blockIdx.y;
  const int h = gh >> 3;
  const int q0 = tile * 64;
  const int kbase = q0 - 127;

  __shared__ unsigned short Qsh[64][72];
  __shared__ unsigned short Ksh[192][72];
  __shared__ unsigned short Vt[64][200];    // transposed V: [dim][key]
  __shared__ float rowpart[4][64];
  __shared__ float invsum[64];
  unsigned short (*Wsh)[200] = (unsigned short (*)[200])Ksh;  // overlay after scores

  const int tid = threadIdx.x;

  // ---- stage Q with RoPE
  {
    int r = tid >> 2, cp = tid & 3;
    int i = q0 + r;
    const unsigned short* qp = &qkv[(size_t)i * QKVD + gh * 64 + cp * 8];
    short8 xa = *(const short8*)qp;
    short8 xb = *(const short8*)(qp + 32);
    short8 oa, ob;
    #pragma unroll
    for (int e = 0; e < 8; ++e) {
      float c = ctab[i * 32 + cp * 8 + e], s = stab[i * 32 + cp * 8 + e];
      float x1 = bf2f((unsigned short)xa[e]), x2 = bf2f((unsigned short)xb[e]);
      oa[e] = (short)f2bf(x1 * c - x2 * s);
      ob[e] = (short)f2bf(x2 * c + x1 * s);
    }
    *(short8*)&Qsh[r][cp * 8] = oa;
    *(short8*)&Qsh[r][cp * 8 + 32] = ob;
  }
  // ---- stage K with RoPE, zero-fill out-of-range
  #pragma unroll
  for (int it = 0; it < 3; ++it) {
    int lin = tid + it * 256;
    int r = lin >> 2, cp = lin & 3;
    int j = kbase + r;
    short8 oa = {}, ob = {};
    if (j >= 0 && j < NTOK) {
      const unsigned short* kp = &qkv[(size_t)j * QKVD + KOFF + h * 64 + cp * 8];
      short8 xa = *(const short8*)kp;
      short8 xb = *(const short8*)(kp + 32);
      #pragma unroll
      for (int e = 0; e < 8; ++e) {
        float c = ctab[j * 32 + cp * 8 + e], s = stab[j * 32 + cp * 8 + e];
        float x1 = bf2f((unsigned short)xa[e]), x2 = bf2f((unsigned short)xb[e]);
        oa[e] = (short)f2bf(x1 * c - x2 * s);
        ob[e] = (short)f2bf(x2 * c + x1 * s);
      }
    }
    *(short8*)&Ksh[r][cp * 8] = oa;
    *(short8*)&Ksh[r][cp * 8 + 32] = ob;
  }
  // ---- stage V transposed
  #pragma unroll
  for (int c = 0; c < 6; ++c) {
    int lin = tid + c * 256;
    int r = lin >> 3, ch = (lin & 7) * 8;
    int j = kbase + r;
    uint4 v = make_uint4(0u, 0u, 0u, 0u);
    if (j >= 0 && j < NTOK) v = *(const uint4*)&qkv[(size_t)j * QKVD + VOFF + h * 64 + ch];
    const unsigned short* vs = (const unsigned short*)&v;
    #pragma unroll
    for (int i2 = 0; i2 < 8; ++i2) Vt[ch + i2][r] = vs[i2];
  }
  __syncthreads();

  const int lane = tid & 63;
  const int wid = tid >> 6;
  const int fr = lane & 15;
  const int fq = lane >> 4;
  const int fc = fq * 8;
  const int wk0 = wid * 48;

  // ---- scores: S[64][48] per wave
  f32x4 sc[4][3] = {};
  #pragma unroll
  for (int k0 = 0; k0 < 64; k0 += 32) {
    short8 qa[4], kb[3];
    #pragma unroll
    for (int mi = 0; mi < 4; ++mi) qa[mi] = *(const short8*)&Qsh[mi * 16 + fr][k0 + fc];
    #pragma unroll
    for (int ni = 0; ni < 3; ++ni) kb[ni] = *(const short8*)&Ksh[wk0 + ni * 16 + fr][k0 + fc];
    #pragma unroll
    for (int mi = 0; mi < 4; ++mi)
      #pragma unroll
      for (int ni = 0; ni < 3; ++ni)
        sc[mi][ni] = MFMA16(qa[mi], kb[ni], sc[mi][ni]);
  }

  // ---- mask + exp in-register; per-row partial sums
  float rsum[4][4];
  #pragma unroll
  for (int mi = 0; mi < 4; ++mi)
    #pragma unroll
    for (int r = 0; r < 4; ++r) {
      int i = q0 + mi * 16 + fq * 4 + r;
      float rs = 0.f;
      #pragma unroll
      for (int ni = 0; ni < 3; ++ni) {
        int kk = wk0 + ni * 16 + fr;
        int j = kbase + kk;
        bool valid = (j >= 0) && (j <= i) && (j > i - 128);
        float pw = valid ? __expf(sc[mi][ni][r] * 0.125f) : 0.f;
        sc[mi][ni][r] = pw;
        rs += pw;
      }
      rs += __shfl_xor(rs, 1);
      rs += __shfl_xor(rs, 2);
      rs += __shfl_xor(rs, 4);
      rs += __shfl_xor(rs, 8);
      rsum[mi][r] = rs;
    }

  __syncthreads();   // all Ksh reads complete; safe to overlay Wsh

  #pragma unroll
  for (int mi = 0; mi < 4; ++mi)
    #pragma unroll
    for (int r = 0; r < 4; ++r) {
      int row = mi * 16 + fq * 4 + r;
      #pragma unroll
      for (int ni = 0; ni < 3; ++ni)
        Wsh[row][wk0 + ni * 16 + fr] = f2bf(sc[mi][ni][r]);
      if (fr == 0) rowpart[wid][row] = rsum[mi][r];
    }
  __syncthreads();

  if (tid < 64) {
    float tot = rowpart[0][tid] + rowpart[1][tid] + rowpart[2][tid] + rowpart[3][tid];
    invsum[tid] = 1.f / (tot + __expf(sinks[gh]));
  }

  // ---- PV: out[64][16] per wave, K=192
  f32x4 pv[4] = {};
  #pragma unroll
  for (int k0 = 0; k0 < 192; k0 += 32) {
    short8 pa[4];
    #pragma unroll
    for (int mi = 0; mi < 4; ++mi) pa[mi] = *(const short8*)&Wsh[mi * 16 + fr][k0 + fc];
    short8 vb = *(const short8*)&Vt[wid * 16 + fr][k0 + fc];
    #pragma unroll
    for (int mi = 0; mi < 4; ++mi)
      pv[mi] = MFMA16(pa[mi], vb, pv[mi]);
  }
  __syncthreads();   // invsum visible

  #pragma unroll
  for (int mi = 0; mi < 4; ++mi)
    #pragma unroll
    for (int r = 0; r < 4; ++r) {
      int row = mi * 16 + fq * 4 + r;
      float inv = invsum[row];
      int col = wid * 16 + fr;
      attn[(size_t)(q0 + row) * ATTD + gh * 64 + col] = f2bf(pv[mi][r] * inv);
    }
}

extern "C" void kernel_launch(void* const* d_in, const int* in_sizes, int n_in,
                              void* d_out, int out_size, void* d_ws, size_t ws_size,
                              hipStream_t stream) {
  const float* x          = (const float*)d_in[0];
  const float* norm_scale = (const float*)d_in[1];
  const float* sinks      = (const float*)d_in[2];
  const float* w_qkv      = (const float*)d_in[3];
  const float* b_qkv      = (const float*)d_in[4];
  const float* w_out      = (const float*)d_in[5];
  const float* b_out      = (const float*)d_in[6];
  float* out = (float*)d_out;

  // workspace:
  //   [0, 21.0MB)     qkv_bf  (2048x5120 bf16, pre-RoPE)
  //   [21.0, 37.8MB)  t_bf (11.8MB, dead after gemm1) overlaid by attn_b (16.8MB)
  //   [37.8, 67.3MB)  wbf (w_qkv_bf 29.5MB, then w_out_bf 23.6MB)
  //   [67.3, 67.9MB)  ctab, stab
  char* ws = (char*)d_ws;
  unsigned short* qkv_bf = (unsigned short*)(ws);
  unsigned short* t_bf   = (unsigned short*)(ws + 20971520);
  unsigned short* attn_b = (unsigned short*)(ws + 20971520);
  unsigned short* wbf    = (unsigned short*)(ws + 20971520 + 16777216);
  float*          ctab   = (float*)(ws + 20971520 + 16777216 + 29491200);
  float*          stab   = ctab + NTOK * 32;

  rope_table_kernel<<<dim3(256), dim3(256), 0, stream>>>(ctab, stab);
  rmsnorm_kernel<<<dim3(NTOK), dim3(256), 0, stream>>>(x, norm_scale, t_bf);
  // w_qkv: 5120x2880 fp32 -> bf16
  cvt_w_kernel<<<dim3(14400), dim3(256), 0, stream>>>(w_qkv, wbf, 3686400L);
  // GEMM1: 2048x5120x2880, tiles 128x320 -> 16x16 = 256 blocks
  gemm4p_kernel<320, false><<<dim3(256), dim3(512), 0, stream>>>(
      t_bf, wbf, b_qkv, nullptr, (void*)qkv_bf, HID, QKVD);
  attn_kernel<<<dim3(32, 64), dim3(256), 0, stream>>>(qkv_bf, sinks, ctab, stab, attn_b);
  // w_out: 2880x4096 fp32 -> bf16
  cvt_w_kernel<<<dim3(11520), dim3(256), 0, stream>>>(w_out, wbf, 2949120L);
  // GEMM2: 2048x2880x4096, tiles 128x192 -> 16x15 = 240 blocks
  gemm4p_kernel<192, true><<<dim3(240), dim3(512), 0, stream>>>(
      attn_b, wbf, b_out, x, (void*)out, ATTD, HID);
}

// Round 9
// 250.502 us; speedup vs baseline: 1.5613x; 1.0713x over previous
//
#include <hip/hip_runtime.h>
#include <hip/hip_bf16.h>
#include <math.h>

typedef __attribute__((ext_vector_type(8))) short short8;
typedef __attribute__((ext_vector_type(4))) float f32x4;

#define NTOK 2048
#define HID  2880
#define QKVD 5120
#define KOFF 4096
#define VOFF 4608
#define ATTD 4096   // N_HEADS*HEAD_DIM

__device__ __forceinline__ unsigned short f2bf(float f) {
  union { float f; unsigned int u; } v; v.f = f;
  unsigned int u = v.u;
  unsigned int r = (u + 0x7FFFu + ((u >> 16) & 1u)) >> 16;
  return (unsigned short)r;
}
__device__ __forceinline__ float bf2f(unsigned short h) {
  union { unsigned int u; float f; } v; v.u = ((unsigned int)h) << 16; return v.f;
}
__device__ __forceinline__ void gload_lds16(const unsigned short* g, unsigned short* l) {
  __builtin_amdgcn_global_load_lds(
      (const __attribute__((address_space(1))) unsigned int*)g,
      (__attribute__((address_space(3))) unsigned int*)l, 16, 0, 0);
}
#define MFMA16(a, b, c) __builtin_amdgcn_mfma_f32_16x16x32_bf16((a), (b), (c), 0, 0, 0)

// ---------------- RoPE cos/sin table (YaRN) ----------------
__global__ void rope_table_kernel(float* __restrict__ ctab, float* __restrict__ stab) {
  int idx = blockIdx.x * 256 + threadIdx.x;
  if (idx >= NTOK * 32) return;
  int pos = idx >> 5, i = idx & 31;
  const double theta = 150000.0;
  const double two_pi = 6.283185307179586476925286766559;
  double freq = pow(theta, (double)i / 32.0);
  double interp = 1.0 / (32.0 * freq);
  double extrap = 1.0 / freq;
  double low  = 32.0 * log(4096.0 / (32.0 * two_pi)) / log(theta);
  double high = 32.0 * log(4096.0 / (1.0  * two_pi)) / log(theta);
  double ramp = ((double)i - low) / (high - low);
  ramp = ramp < 0.0 ? 0.0 : (ramp > 1.0 ? 1.0 : ramp);
  double maskv = 1.0 - ramp;
  double inv = interp * (1.0 - maskv) + extrap * maskv;
  double ang = (double)pos * inv;
  double conc = 0.1 * log(32.0) + 1.0;
  ctab[idx] = (float)(cos(ang) * conc);
  stab[idx] = (float)(sin(ang) * conc);
}

// ---------------- RMSNorm fp32 -> bf16 (vectorized) ----------------
__global__ __launch_bounds__(256) void rmsnorm_kernel(
    const float* __restrict__ x, const float* __restrict__ scale,
    unsigned short* __restrict__ t) {
  int row = blockIdx.x;
  const float4* xr = (const float4*)(x + (size_t)row * HID);
  const float4* sc = (const float4*)scale;
  float ss = 0.f;
  for (int c = threadIdx.x; c < HID / 4; c += 256) {
    float4 v = xr[c];
    ss += v.x * v.x + v.y * v.y + v.z * v.z + v.w * v.w;
  }
  #pragma unroll
  for (int m = 1; m < 64; m <<= 1) ss += __shfl_xor(ss, m);
  __shared__ float red[4];
  if ((threadIdx.x & 63) == 0) red[threadIdx.x >> 6] = ss;
  __syncthreads();
  float tot = red[0] + red[1] + red[2] + red[3];
  float rs = rsqrtf(tot / (float)HID + 1e-5f);
  for (int c = threadIdx.x; c < HID / 4; c += 256) {
    float4 v = xr[c];
    float4 s4 = sc[c];
    ushort4 o;
    o.x = f2bf(v.x * rs * s4.x); o.y = f2bf(v.y * rs * s4.y);
    o.z = f2bf(v.z * rs * s4.z); o.w = f2bf(v.w * rs * s4.w);
    *(ushort4*)&t[(size_t)row * HID + c * 4] = o;
  }
}

// ---------------- Pipelined GEMM with fused fp32->bf16 B staging ----------
// C[M,NC] = A[M,K]bf16 @ Bf[NC,K]fp32^T (+bias, +resid)
// BM=128, BN in {320,192}; BK=64; 512 thr = 8 waves (2M x 4N); dbuf LDS,
// 3-bit T2 swizzle. Per tile: [NB*2 fp32 B-reg loads (t+1)] [2 A gloads (t+1)]
// vmcnt(NB*2+2) barrier | ds_read+MFMA | vmcnt(2) cvt_pk+ds_write B(t+1)
// lgkmcnt(0) barrier. vmcnt never drains to 0 mid-loop (T4).
template<int BN, bool RESID>
__global__ __launch_bounds__(512, 2) void gemmf_kernel(
    const unsigned short* __restrict__ A, const float* __restrict__ Bf,
    const float* __restrict__ bias, const float* __restrict__ resid,
    void* __restrict__ Cout, int K, int NC) {
  constexpr int NF = BN / 64;         // N-frags per wave (5 or 3)
  constexpr int NB = BN / 64;         // B slices (64 rows each)
  __shared__ unsigned short sA[2][8192];       // 128x64 bf16 per buf
  __shared__ unsigned short sB[2][BN * 64];

  const int tid = threadIdx.x;
  // XCD-aware swizzle (grid % 8 == 0 for both launches)
  const int q8 = gridDim.x >> 3;
  const int sw = ((int)blockIdx.x & 7) * q8 + ((int)blockIdx.x >> 3);
  const int m0 = (sw & 15) * 128;
  const int n0 = (sw >> 4) * BN;

  const int lane = tid & 63, wid = tid >> 6;
  const int fr = lane & 15, fq = lane >> 4;
  const int wr = wid >> 2, wc = wid & 3;
  const int swz = (fr & 7) << 4;                     // read-side XOR (byte bits 4,5,6)
  const int r_st = tid >> 3;                         // staged row within 64-row slice
  const int c8_st = ((tid & 7) ^ ((tid >> 3) & 7)) * 8;  // inverse-swizzled source chunk
  const int wlds = wid << 9;                         // wave's 1KB chunk (ushort units)

  const unsigned short* Ag = A + (size_t)(m0 + r_st) * K + c8_st;
  const float* Bgf = Bf + (size_t)(n0 + r_st) * K + c8_st;

  f32x4 acc[4][NF] = {};
  const int NT = K >> 6;

  auto LDA_ = [&](int bs, int mf, int ks) -> short8 {
    int row = wr * 64 + mf * 16 + fr;                // row&7 == fr&7
    int cb = (ks * 64 + fq * 16) ^ swz;
    return *(const short8*)((const char*)&sA[bs][0] + row * 128 + cb);
  };
  auto LDB_ = [&](int bs, int nf, int ks) -> short8 {
    int row = wc * (NF * 16) + nf * 16 + fr;         // row&7 == fr&7
    int cb = (ks * 64 + fq * 16) ^ swz;
    return *(const short8*)((const char*)&sB[bs][0] + row * 128 + cb);
  };
  auto stA = [&](int tt, int b, int s) {
    gload_lds16(Ag + (size_t)tt * 64 + (size_t)(s * 64) * K, &sA[b][s * 4096 + wlds]);
  };
  // cvt 8 fp32 -> 8 bf16, one ds_write_b128 (same layout as gload_lds dest)
  auto writeB = [&](int b, int s, const float4& lo, const float4& hi) {
    unsigned int w0, w1, w2, w3;
    asm("v_cvt_pk_bf16_f32 %0, %1, %2" : "=v"(w0) : "v"(lo.x), "v"(lo.y));
    asm("v_cvt_pk_bf16_f32 %0, %1, %2" : "=v"(w1) : "v"(lo.z), "v"(lo.w));
    asm("v_cvt_pk_bf16_f32 %0, %1, %2" : "=v"(w2) : "v"(hi.x), "v"(hi.y));
    asm("v_cvt_pk_bf16_f32 %0, %1, %2" : "=v"(w3) : "v"(hi.z), "v"(hi.w));
    *(uint4*)((char*)&sB[b][0] + s * 8192 + wid * 1024 + lane * 16) =
        make_uint4(w0, w1, w2, w3);
  };

  float4 rbl[NB], rbh[NB];

  // -------- prologue: load B0 fp32 -> regs, issue A0 gloads, write sB[0]
  #pragma unroll
  for (int s = 0; s < NB; ++s) {
    const float* p = Bgf + (size_t)(s * 64) * K;
    rbl[s] = *(const float4*)p;
    rbh[s] = *(const float4*)(p + 4);
  }
  stA(0, 0, 0); stA(0, 0, 1);
  asm volatile("s_waitcnt vmcnt(2)" ::: "memory");   // B0 done; A0 in flight
  #pragma unroll
  for (int s = 0; s < NB; ++s) writeB(0, s, rbl[s], rbh[s]);
  asm volatile("s_waitcnt lgkmcnt(0)" ::: "memory");

  for (int t = 0; t < NT; ++t) {
    const int cu = t & 1, nx = cu ^ 1;
    const bool pf = (t + 1 < NT);
    // ---- issue tile t+1: B fp32 -> regs, A -> LDS; ONE counted wait for A(t)
    if (pf) {
      #pragma unroll
      for (int s = 0; s < NB; ++s) {
        const float* p = Bgf + (size_t)(t + 1) * 64 + (size_t)(s * 64) * K;
        rbl[s] = *(const float4*)p;
        rbh[s] = *(const float4*)(p + 4);
      }
      stA(t + 1, nx, 0); stA(t + 1, nx, 1);
      if constexpr (NB == 5) asm volatile("s_waitcnt vmcnt(12)" ::: "memory");
      else                   asm volatile("s_waitcnt vmcnt(8)" ::: "memory");
    } else {
      asm volatile("s_waitcnt vmcnt(0)" ::: "memory");
    }
    __builtin_amdgcn_s_barrier();          // all waves' tile-t data ready
    __builtin_amdgcn_sched_barrier(0);
    // ---- compute on buf cu; compiler emits fine-grained lgkmcnt
    #pragma unroll
    for (int ks = 0; ks < 2; ++ks) {
      short8 afr[4], bfr[NF];
      #pragma unroll
      for (int mf = 0; mf < 4; ++mf) afr[mf] = LDA_(cu, mf, ks);
      #pragma unroll
      for (int nf = 0; nf < NF; ++nf) bfr[nf] = LDB_(cu, nf, ks);
      __builtin_amdgcn_s_setprio(1);
      #pragma unroll
      for (int mf = 0; mf < 4; ++mf)
        #pragma unroll
        for (int nf = 0; nf < NF; ++nf)
          acc[mf][nf] = MFMA16(afr[mf], bfr[nf], acc[mf][nf]);
      __builtin_amdgcn_s_setprio(0);
    }
    // ---- convert+write B(t+1) into buf nx (B-reg loads have full-tile slack)
    if (pf) {
      asm volatile("s_waitcnt vmcnt(2)" ::: "memory");  // B-regs done; A(t+1) in flight
      #pragma unroll
      for (int s = 0; s < NB; ++s) writeB(nx, s, rbl[s], rbh[s]);
    }
    asm volatile("s_waitcnt lgkmcnt(0)" ::: "memory");  // drain ds_writes
    __builtin_amdgcn_s_barrier();
  }

  // -------- epilogue
  if (!RESID) {
    unsigned short* C = (unsigned short*)Cout;
    #pragma unroll
    for (int mf = 0; mf < 4; ++mf)
      #pragma unroll
      for (int nf = 0; nf < NF; ++nf)
        #pragma unroll
        for (int r = 0; r < 4; ++r) {
          int row = m0 + wr * 64 + mf * 16 + fq * 4 + r;
          int col = n0 + wc * (NF * 16) + nf * 16 + fr;
          C[(size_t)row * NC + col] = f2bf(acc[mf][nf][r] + bias[col]);
        }
  } else {
    float* C = (float*)Cout;
    #pragma unroll
    for (int mf = 0; mf < 4; ++mf)
      #pragma unroll
      for (int nf = 0; nf < NF; ++nf)
        #pragma unroll
        for (int r = 0; r < 4; ++r) {
          int row = m0 + wr * 64 + mf * 16 + fq * 4 + r;
          int col = n0 + wc * (NF * 16) + nf * 16 + fr;
          C[(size_t)row * NC + col] = acc[mf][nf][r] + bias[col] + resid[(size_t)row * NC + col];
        }
  }
}

// ---------------- MFMA sliding-window attention with sinks + fused RoPE ----------------
__global__ __launch_bounds__(256) void attn_kernel(
    const unsigned short* __restrict__ qkv, const float* __restrict__ sinks,
    const float* __restrict__ ctab, const float* __restrict__ stab,
    unsigned short* __restrict__ attn) {
  const int tile = blockIdx.x;
  const int gh = blockIdx.y;
  const int h = gh >> 3;
  const int q0 = tile * 64;
  const int kbase = q0 - 127;

  __shared__ unsigned short Qsh[64][72];
  __shared__ unsigned short Ksh[192][72];
  __shared__ unsigned short Vt[64][200];    // transposed V: [dim][key]
  __shared__ float rowpart[4][64];
  __shared__ float invsum[64];
  unsigned short (*Wsh)[200] = (unsigned short (*)[200])Ksh;  // overlay after scores

  const int tid = threadIdx.x;

  // ---- stage Q with RoPE
  {
    int r = tid >> 2, cp = tid & 3;
    int i = q0 + r;
    const unsigned short* qp = &qkv[(size_t)i * QKVD + gh * 64 + cp * 8];
    short8 xa = *(const short8*)qp;
    short8 xb = *(const short8*)(qp + 32);
    short8 oa, ob;
    #pragma unroll
    for (int e = 0; e < 8; ++e) {
      float c = ctab[i * 32 + cp * 8 + e], s = stab[i * 32 + cp * 8 + e];
      float x1 = bf2f((unsigned short)xa[e]), x2 = bf2f((unsigned short)xb[e]);
      oa[e] = (short)f2bf(x1 * c - x2 * s);
      ob[e] = (short)f2bf(x2 * c + x1 * s);
    }
    *(short8*)&Qsh[r][cp * 8] = oa;
    *(short8*)&Qsh[r][cp * 8 + 32] = ob;
  }
  // ---- stage K with RoPE, zero-fill out-of-range
  #pragma unroll
  for (int it = 0; it < 3; ++it) {
    int lin = tid + it * 256;
    int r = lin >> 2, cp = lin & 3;
    int j = kbase + r;
    short8 oa = {}, ob = {};
    if (j >= 0 && j < NTOK) {
      const unsigned short* kp = &qkv[(size_t)j * QKVD + KOFF + h * 64 + cp * 8];
      short8 xa = *(const short8*)kp;
      short8 xb = *(const short8*)(kp + 32);
      #pragma unroll
      for (int e = 0; e < 8; ++e) {
        float c = ctab[j * 32 + cp * 8 + e], s = stab[j * 32 + cp * 8 + e];
        float x1 = bf2f((unsigned short)xa[e]), x2 = bf2f((unsigned short)xb[e]);
        oa[e] = (short)f2bf(x1 * c - x2 * s);
        ob[e] = (short)f2bf(x2 * c + x1 * s);
      }
    }
    *(short8*)&Ksh[r][cp * 8] = oa;
    *(short8*)&Ksh[r][cp * 8 + 32] = ob;
  }
  // ---- stage V transposed
  #pragma unroll
  for (int c = 0; c < 6; ++c) {
    int lin = tid + c * 256;
    int r = lin >> 3, ch = (lin & 7) * 8;
    int j = kbase + r;
    uint4 v = make_uint4(0u, 0u, 0u, 0u);
    if (j >= 0 && j < NTOK) v = *(const uint4*)&qkv[(size_t)j * QKVD + VOFF + h * 64 + ch];
    const unsigned short* vs = (const unsigned short*)&v;
    #pragma unroll
    for (int i2 = 0; i2 < 8; ++i2) Vt[ch + i2][r] = vs[i2];
  }
  __syncthreads();

  const int lane = tid & 63;
  const int wid = tid >> 6;
  const int fr = lane & 15;
  const int fq = lane >> 4;
  const int fc = fq * 8;
  const int wk0 = wid * 48;

  // ---- scores: S[64][48] per wave
  f32x4 sc[4][3] = {};
  #pragma unroll
  for (int k0 = 0; k0 < 64; k0 += 32) {
    short8 qa[4], kb[3];
    #pragma unroll
    for (int mi = 0; mi < 4; ++mi) qa[mi] = *(const short8*)&Qsh[mi * 16 + fr][k0 + fc];
    #pragma unroll
    for (int ni = 0; ni < 3; ++ni) kb[ni] = *(const short8*)&Ksh[wk0 + ni * 16 + fr][k0 + fc];
    #pragma unroll
    for (int mi = 0; mi < 4; ++mi)
      #pragma unroll
      for (int ni = 0; ni < 3; ++ni)
        sc[mi][ni] = MFMA16(qa[mi], kb[ni], sc[mi][ni]);
  }

  // ---- mask + exp in-register; per-row partial sums
  float rsum[4][4];
  #pragma unroll
  for (int mi = 0; mi < 4; ++mi)
    #pragma unroll
    for (int r = 0; r < 4; ++r) {
      int i = q0 + mi * 16 + fq * 4 + r;
      float rs = 0.f;
      #pragma unroll
      for (int ni = 0; ni < 3; ++ni) {
        int kk = wk0 + ni * 16 + fr;
        int j = kbase + kk;
        bool valid = (j >= 0) && (j <= i) && (j > i - 128);
        float pw = valid ? __expf(sc[mi][ni][r] * 0.125f) : 0.f;
        sc[mi][ni][r] = pw;
        rs += pw;
      }
      rs += __shfl_xor(rs, 1);
      rs += __shfl_xor(rs, 2);
      rs += __shfl_xor(rs, 4);
      rs += __shfl_xor(rs, 8);
      rsum[mi][r] = rs;
    }

  __syncthreads();   // all Ksh reads complete; safe to overlay Wsh

  #pragma unroll
  for (int mi = 0; mi < 4; ++mi)
    #pragma unroll
    for (int r = 0; r < 4; ++r) {
      int row = mi * 16 + fq * 4 + r;
      #pragma unroll
      for (int ni = 0; ni < 3; ++ni)
        Wsh[row][wk0 + ni * 16 + fr] = f2bf(sc[mi][ni][r]);
      if (fr == 0) rowpart[wid][row] = rsum[mi][r];
    }
  __syncthreads();

  if (tid < 64) {
    float tot = rowpart[0][tid] + rowpart[1][tid] + rowpart[2][tid] + rowpart[3][tid];
    invsum[tid] = 1.f / (tot + __expf(sinks[gh]));
  }

  // ---- PV: out[64][16] per wave, K=192
  f32x4 pv[4] = {};
  #pragma unroll
  for (int k0 = 0; k0 < 192; k0 += 32) {
    short8 pa[4];
    #pragma unroll
    for (int mi = 0; mi < 4; ++mi) pa[mi] = *(const short8*)&Wsh[mi * 16 + fr][k0 + fc];
    short8 vb = *(const short8*)&Vt[wid * 16 + fr][k0 + fc];
    #pragma unroll
    for (int mi = 0; mi < 4; ++mi)
      pv[mi] = MFMA16(pa[mi], vb, pv[mi]);
  }
  __syncthreads();   // invsum visible

  #pragma unroll
  for (int mi = 0; mi < 4; ++mi)
    #pragma unroll
    for (int r = 0; r < 4; ++r) {
      int row = mi * 16 + fq * 4 + r;
      float inv = invsum[row];
      int col = wid * 16 + fr;
      attn[(size_t)(q0 + row) * ATTD + gh * 64 + col] = f2bf(pv[mi][r] * inv);
    }
}

extern "C" void kernel_launch(void* const* d_in, const int* in_sizes, int n_in,
                              void* d_out, int out_size, void* d_ws, size_t ws_size,
                              hipStream_t stream) {
  const float* x          = (const float*)d_in[0];
  const float* norm_scale = (const float*)d_in[1];
  const float* sinks      = (const float*)d_in[2];
  const float* w_qkv      = (const float*)d_in[3];
  const float* b_qkv      = (const float*)d_in[4];
  const float* w_out      = (const float*)d_in[5];
  const float* b_out      = (const float*)d_in[6];
  float* out = (float*)d_out;

  // workspace:
  //   [0, 21.0MB)     qkv_bf  (2048x5120 bf16, pre-RoPE)
  //   [21.0, 37.8MB)  t_bf (11.8MB, dead after gemm1) overlaid by attn_b (16.8MB)
  //   [37.8, 38.3MB)  ctab, stab
  char* ws = (char*)d_ws;
  unsigned short* qkv_bf = (unsigned short*)(ws);
  unsigned short* t_bf   = (unsigned short*)(ws + 20971520);
  unsigned short* attn_b = (unsigned short*)(ws + 20971520);
  float*          ctab   = (float*)(ws + 20971520 + 16777216);
  float*          stab   = ctab + NTOK * 32;

  rope_table_kernel<<<dim3(256), dim3(256), 0, stream>>>(ctab, stab);
  rmsnorm_kernel<<<dim3(NTOK), dim3(256), 0, stream>>>(x, norm_scale, t_bf);
  // GEMM1: 2048x5120x2880, tiles 128x320 -> 16x16 = 256 blocks; B = w_qkv fp32 direct
  gemmf_kernel<320, false><<<dim3(256), dim3(512), 0, stream>>>(
      t_bf, w_qkv, b_qkv, nullptr, (void*)qkv_bf, HID, QKVD);
  attn_kernel<<<dim3(32, 64), dim3(256), 0, stream>>>(qkv_bf, sinks, ctab, stab, attn_b);
  // GEMM2: 2048x2880x4096, tiles 128x192 -> 16x15 = 240 blocks; B = w_out fp32 direct
  gemmf_kernel<192, true><<<dim3(240), dim3(512), 0, stream>>>(
      attn_b, w_out, b_out, x, (void*)out, ATTD, HID);
}

// Round 10
// 230.781 us; speedup vs baseline: 1.6947x; 1.0855x over previous
//
#include <hip/hip_runtime.h>
#include <hip/hip_bf16.h>
#include <math.h>

typedef __attribute__((ext_vector_type(8))) short short8;
typedef __attribute__((ext_vector_type(4))) float f32x4;

#define NTOK 2048
#define HID  2880
#define QKVD 5120
#define KOFF 4096
#define VOFF 4608
#define ATTD 4096   // N_HEADS*HEAD_DIM

__device__ __forceinline__ unsigned short f2bf(float f) {
  union { float f; unsigned int u; } v; v.f = f;
  unsigned int u = v.u;
  unsigned int r = (u + 0x7FFFu + ((u >> 16) & 1u)) >> 16;
  return (unsigned short)r;
}
__device__ __forceinline__ float bf2f(unsigned short h) {
  union { unsigned int u; float f; } v; v.u = ((unsigned int)h) << 16; return v.f;
}
__device__ __forceinline__ void gload_lds16(const unsigned short* g, unsigned short* l) {
  __builtin_amdgcn_global_load_lds(
      (const __attribute__((address_space(1))) unsigned int*)g,
      (__attribute__((address_space(3))) unsigned int*)l, 16, 0, 0);
}
#define MFMA16(a, b, c) __builtin_amdgcn_mfma_f32_16x16x32_bf16((a), (b), (c), 0, 0, 0)

// ---------------- RoPE cos/sin table (YaRN) ----------------
__global__ void rope_table_kernel(float* __restrict__ ctab, float* __restrict__ stab) {
  int idx = blockIdx.x * 256 + threadIdx.x;
  if (idx >= NTOK * 32) return;
  int pos = idx >> 5, i = idx & 31;
  const double theta = 150000.0;
  const double two_pi = 6.283185307179586476925286766559;
  double freq = pow(theta, (double)i / 32.0);
  double interp = 1.0 / (32.0 * freq);
  double extrap = 1.0 / freq;
  double low  = 32.0 * log(4096.0 / (32.0 * two_pi)) / log(theta);
  double high = 32.0 * log(4096.0 / (1.0  * two_pi)) / log(theta);
  double ramp = ((double)i - low) / (high - low);
  ramp = ramp < 0.0 ? 0.0 : (ramp > 1.0 ? 1.0 : ramp);
  double maskv = 1.0 - ramp;
  double inv = interp * (1.0 - maskv) + extrap * maskv;
  double ang = (double)pos * inv;
  double conc = 0.1 * log(32.0) + 1.0;
  ctab[idx] = (float)(cos(ang) * conc);
  stab[idx] = (float)(sin(ang) * conc);
}

// ---------------- RMSNorm fp32 -> bf16 (vectorized) ----------------
__global__ __launch_bounds__(256) void rmsnorm_kernel(
    const float* __restrict__ x, const float* __restrict__ scale,
    unsigned short* __restrict__ t) {
  int row = blockIdx.x;
  const float4* xr = (const float4*)(x + (size_t)row * HID);
  const float4* sc = (const float4*)scale;
  float ss = 0.f;
  for (int c = threadIdx.x; c < HID / 4; c += 256) {
    float4 v = xr[c];
    ss += v.x * v.x + v.y * v.y + v.z * v.z + v.w * v.w;
  }
  #pragma unroll
  for (int m = 1; m < 64; m <<= 1) ss += __shfl_xor(ss, m);
  __shared__ float red[4];
  if ((threadIdx.x & 63) == 0) red[threadIdx.x >> 6] = ss;
  __syncthreads();
  float tot = red[0] + red[1] + red[2] + red[3];
  float rs = rsqrtf(tot / (float)HID + 1e-5f);
  for (int c = threadIdx.x; c < HID / 4; c += 256) {
    float4 v = xr[c];
    float4 s4 = sc[c];
    ushort4 o;
    o.x = f2bf(v.x * rs * s4.x); o.y = f2bf(v.y * rs * s4.y);
    o.z = f2bf(v.z * rs * s4.z); o.w = f2bf(v.w * rs * s4.w);
    *(ushort4*)&t[(size_t)row * HID + c * 4] = o;
  }
}

// ---------------- Weight fp32 -> bf16 ----------------
__global__ __launch_bounds__(256) void cvt_w_kernel(
    const float* __restrict__ w, unsigned short* __restrict__ wb, long total4) {
  long idx = (long)blockIdx.x * 256 + threadIdx.x;
  if (idx >= total4) return;
  long base = idx * 4;
  float4 v = *(const float4*)&w[base];
  ushort4 o;
  o.x = f2bf(v.x); o.y = f2bf(v.y); o.z = f2bf(v.z); o.w = f2bf(v.w);
  *(ushort4*)&wb[base] = o;
}

// ---------------- Pipelined GEMM (R5 structure + full-tile fragment preload) ----
// C[M,NC] = A[M,K]bf16 @ B[NC,K]bf16^T (+bias, +resid)
// BM=128, BN in {320,192}; BK=64; 512 thr = 8 waves (2M x 4N); dbuf LDS,
// 3-bit T2 swizzle; per tile: issue S loads -> vmcnt(S) -> barrier ->
// [ALL 18 ds_reads, then 40 MFMAs] -> barrier. vmcnt never drains to 0 (T4).
template<int BN, bool RESID>
__global__ __launch_bounds__(512, 2) void gemm8p_kernel(
    const unsigned short* __restrict__ A, const unsigned short* __restrict__ B,
    const float* __restrict__ bias, const float* __restrict__ resid,
    void* __restrict__ Cout, int K, int NC) {
  constexpr int NF = BN / 64;         // N-frags per wave (5 or 3)
  constexpr int NB = BN / 64;         // B slices (64 rows each)
  __shared__ unsigned short sA[2][8192];       // 128x64 bf16 per buf
  __shared__ unsigned short sB[2][BN * 64];

  const int tid = threadIdx.x;
  // XCD-aware swizzle (grid % 8 == 0 for both launches)
  const int q8 = gridDim.x >> 3;
  const int sw = ((int)blockIdx.x & 7) * q8 + ((int)blockIdx.x >> 3);
  const int m0 = (sw & 15) * 128;
  const int n0 = (sw >> 4) * BN;

  const int lane = tid & 63, wid = tid >> 6;
  const int fr = lane & 15, fq = lane >> 4;
  const int wr = wid >> 2, wc = wid & 3;
  const int swz = (fr & 7) << 4;                     // read-side XOR (byte bits 4,5,6)
  const int r_st = tid >> 3;                         // staged row within 64-row slice
  const int c8_st = ((tid & 7) ^ ((tid >> 3) & 7)) * 8;  // inverse-swizzled source chunk
  const int wlds = wid << 9;                         // wave's 1KB chunk (ushort units)

  const unsigned short* Ag = A + (size_t)(m0 + r_st) * K + c8_st;
  const unsigned short* Bg = B + (size_t)(n0 + r_st) * K + c8_st;

  f32x4 acc[4][NF] = {};
  const int NT = K >> 6;

  auto LDA_ = [&](int bs, int mf, int ks) -> short8 {
    int row = wr * 64 + mf * 16 + fr;                // row&7 == fr&7
    int cb = (ks * 64 + fq * 16) ^ swz;
    return *(const short8*)((const char*)&sA[bs][0] + row * 128 + cb);
  };
  auto LDB_ = [&](int bs, int nf, int ks) -> short8 {
    int row = wc * (NF * 16) + nf * 16 + fr;         // row&7 == fr&7
    int cb = (ks * 64 + fq * 16) ^ swz;
    return *(const short8*)((const char*)&sB[bs][0] + row * 128 + cb);
  };
  auto issue_tile = [&](int tt, int b) {
    const unsigned short* Agt = Ag + (size_t)tt * 64;
    const unsigned short* Bgt = Bg + (size_t)tt * 64;
    gload_lds16(Agt, &sA[b][wlds]);
    gload_lds16(Agt + (size_t)64 * K, &sA[b][4096 + wlds]);
    #pragma unroll
    for (int s = 0; s < NB; ++s)
      gload_lds16(Bgt + (size_t)(s * 64) * K, &sB[b][s * 4096 + wlds]);
  };

  // -------- prologue: issue tile 0 into buf 0 (no wait yet)
  issue_tile(0, 0);

  for (int t = 0; t < NT; ++t) {
    const int cu = t & 1;
    // ---- issue tile t+1, then ONE counted wait (completes tile t's loads,
    //      leaves tile t+1's in flight with a full tile of slack).
    if (t + 1 < NT) {
      issue_tile(t + 1, cu ^ 1);
      if constexpr (NB == 5) asm volatile("s_waitcnt vmcnt(7)" ::: "memory");
      else                   asm volatile("s_waitcnt vmcnt(5)" ::: "memory");
    } else {
      asm volatile("s_waitcnt vmcnt(0)" ::: "memory");
    }
    __builtin_amdgcn_s_barrier();          // all waves' tile-t loads complete
    __builtin_amdgcn_sched_barrier(0);     // keep ds_reads below readiness point
    // ---- preload ALL fragments for the tile (both ks halves), then MFMA.
    //      72 VGPRs of read-ahead lets ks=1 reads drain under ks=0 MFMAs.
    short8 afr0[4], bfr0[NF], afr1[4], bfr1[NF];
    #pragma unroll
    for (int mf = 0; mf < 4; ++mf) afr0[mf] = LDA_(cu, mf, 0);
    #pragma unroll
    for (int nf = 0; nf < NF; ++nf) bfr0[nf] = LDB_(cu, nf, 0);
    #pragma unroll
    for (int mf = 0; mf < 4; ++mf) afr1[mf] = LDA_(cu, mf, 1);
    #pragma unroll
    for (int nf = 0; nf < NF; ++nf) bfr1[nf] = LDB_(cu, nf, 1);
    __builtin_amdgcn_s_setprio(1);
    #pragma unroll
    for (int mf = 0; mf < 4; ++mf)
      #pragma unroll
      for (int nf = 0; nf < NF; ++nf)
        acc[mf][nf] = MFMA16(afr0[mf], bfr0[nf], acc[mf][nf]);
    #pragma unroll
    for (int mf = 0; mf < 4; ++mf)
      #pragma unroll
      for (int nf = 0; nf < NF; ++nf)
        acc[mf][nf] = MFMA16(afr1[mf], bfr1[nf], acc[mf][nf]);
    __builtin_amdgcn_s_setprio(0);
    // ---- end of tile: reads from buf cu done -> next iter may stage into it
    __builtin_amdgcn_s_barrier();
  }

  // -------- epilogue
  if (!RESID) {
    unsigned short* C = (unsigned short*)Cout;
    #pragma unroll
    for (int mf = 0; mf < 4; ++mf)
      #pragma unroll
      for (int nf = 0; nf < NF; ++nf)
        #pragma unroll
        for (int r = 0; r < 4; ++r) {
          int row = m0 + wr * 64 + mf * 16 + fq * 4 + r;
          int col = n0 + wc * (NF * 16) + nf * 16 + fr;
          C[(size_t)row * NC + col] = f2bf(acc[mf][nf][r] + bias[col]);
        }
  } else {
    float* C = (float*)Cout;
    #pragma unroll
    for (int mf = 0; mf < 4; ++mf)
      #pragma unroll
      for (int nf = 0; nf < NF; ++nf)
        #pragma unroll
        for (int r = 0; r < 4; ++r) {
          int row = m0 + wr * 64 + mf * 16 + fq * 4 + r;
          int col = n0 + wc * (NF * 16) + nf * 16 + fr;
          C[(size_t)row * NC + col] = acc[mf][nf][r] + bias[col] + resid[(size_t)row * NC + col];
        }
  }
}

// ---------------- MFMA sliding-window attention with sinks + fused RoPE ----------------
__global__ __launch_bounds__(256) void attn_kernel(
    const unsigned short* __restrict__ qkv, const float* __restrict__ sinks,
    const float* __restrict__ ctab, const float* __restrict__ stab,
    unsigned short* __restrict__ attn) {
  const int tile = blockIdx.x;
  const int gh = blockIdx.y;
  const int h = gh >> 3;
  const int q0 = tile * 64;
  const int kbase = q0 - 127;

  __shared__ unsigned short Qsh[64][72];
  __shared__ unsigned short Ksh[192][72];
  __shared__ unsigned short Vt[64][200];    // transposed V: [dim][key]
  __shared__ float rowpart[4][64];
  __shared__ float invsum[64];
  unsigned short (*Wsh)[200] = (unsigned short (*)[200])Ksh;  // overlay after scores

  const int tid = threadIdx.x;

  // ---- stage Q with RoPE
  {
    int r = tid >> 2, cp = tid & 3;
    int i = q0 + r;
    const unsigned short* qp = &qkv[(size_t)i * QKVD + gh * 64 + cp * 8];
    short8 xa = *(const short8*)qp;
    short8 xb = *(const short8*)(qp + 32);
    short8 oa, ob;
    #pragma unroll
    for (int e = 0; e < 8; ++e) {
      float c = ctab[i * 32 + cp * 8 + e], s = stab[i * 32 + cp * 8 + e];
      float x1 = bf2f((unsigned short)xa[e]), x2 = bf2f((unsigned short)xb[e]);
      oa[e] = (short)f2bf(x1 * c - x2 * s);
      ob[e] = (short)f2bf(x2 * c + x1 * s);
    }
    *(short8*)&Qsh[r][cp * 8] = oa;
    *(short8*)&Qsh[r][cp * 8 + 32] = ob;
  }
  // ---- stage K with RoPE, zero-fill out-of-range
  #pragma unroll
  for (int it = 0; it < 3; ++it) {
    int lin = tid + it * 256;
    int r = lin >> 2, cp = lin & 3;
    int j = kbase + r;
    short8 oa = {}, ob = {};
    if (j >= 0 && j < NTOK) {
      const unsigned short* kp = &qkv[(size_t)j * QKVD + KOFF + h * 64 + cp * 8];
      short8 xa = *(const short8*)kp;
      short8 xb = *(const short8*)(kp + 32);
      #pragma unroll
      for (int e = 0; e < 8; ++e) {
        float c = ctab[j * 32 + cp * 8 + e], s = stab[j * 32 + cp * 8 + e];
        float x1 = bf2f((unsigned short)xa[e]), x2 = bf2f((unsigned short)xb[e]);
        oa[e] = (short)f2bf(x1 * c - x2 * s);
        ob[e] = (short)f2bf(x2 * c + x1 * s);
      }
    }
    *(short8*)&Ksh[r][cp * 8] = oa;
    *(short8*)&Ksh[r][cp * 8 + 32] = ob;
  }
  // ---- stage V transposed
  #pragma unroll
  for (int c = 0; c < 6; ++c) {
    int lin = tid + c * 256;
    int r = lin >> 3, ch = (lin & 7) * 8;
    int j = kbase + r;
    uint4 v = make_uint4(0u, 0u, 0u, 0u);
    if (j >= 0 && j < NTOK) v = *(const uint4*)&qkv[(size_t)j * QKVD + VOFF + h * 64 + ch];
    const unsigned short* vs = (const unsigned short*)&v;
    #pragma unroll
    for (int i2 = 0; i2 < 8; ++i2) Vt[ch + i2][r] = vs[i2];
  }
  __syncthreads();

  const int lane = tid & 63;
  const int wid = tid >> 6;
  const int fr = lane & 15;
  const int fq = lane >> 4;
  const int fc = fq * 8;
  const int wk0 = wid * 48;

  // ---- scores: S[64][48] per wave
  f32x4 sc[4][3] = {};
  #pragma unroll
  for (int k0 = 0; k0 < 64; k0 += 32) {
    short8 qa[4], kb[3];
    #pragma unroll
    for (int mi = 0; mi < 4; ++mi) qa[mi] = *(const short8*)&Qsh[mi * 16 + fr][k0 + fc];
    #pragma unroll
    for (int ni = 0; ni < 3; ++ni) kb[ni] = *(const short8*)&Ksh[wk0 + ni * 16 + fr][k0 + fc];
    #pragma unroll
    for (int mi = 0; mi < 4; ++mi)
      #pragma unroll
      for (int ni = 0; ni < 3; ++ni)
        sc[mi][ni] = MFMA16(qa[mi], kb[ni], sc[mi][ni]);
  }

  // ---- mask + exp in-register; per-row partial sums
  float rsum[4][4];
  #pragma unroll
  for (int mi = 0; mi < 4; ++mi)
    #pragma unroll
    for (int r = 0; r < 4; ++r) {
      int i = q0 + mi * 16 + fq * 4 + r;
      float rs = 0.f;
      #pragma unroll
      for (int ni = 0; ni < 3; ++ni) {
        int kk = wk0 + ni * 16 + fr;
        int j = kbase + kk;
        bool valid = (j >= 0) && (j <= i) && (j > i - 128);
        float pw = valid ? __expf(sc[mi][ni][r] * 0.125f) : 0.f;
        sc[mi][ni][r] = pw;
        rs += pw;
      }
      rs += __shfl_xor(rs, 1);
      rs += __shfl_xor(rs, 2);
      rs += __shfl_xor(rs, 4);
      rs += __shfl_xor(rs, 8);
      rsum[mi][r] = rs;
    }

  __syncthreads();   // all Ksh reads complete; safe to overlay Wsh

  #pragma unroll
  for (int mi = 0; mi < 4; ++mi)
    #pragma unroll
    for (int r = 0; r < 4; ++r) {
      int row = mi * 16 + fq * 4 + r;
      #pragma unroll
      for (int ni = 0; ni < 3; ++ni)
        Wsh[row][wk0 + ni * 16 + fr] = f2bf(sc[mi][ni][r]);
      if (fr == 0) rowpart[wid][row] = rsum[mi][r];
    }
  __syncthreads();

  if (tid < 64) {
    float tot = rowpart[0][tid] + rowpart[1][tid] + rowpart[2][tid] + rowpart[3][tid];
    invsum[tid] = 1.f / (tot + __expf(sinks[gh]));
  }

  // ---- PV: out[64][16] per wave, K=192
  f32x4 pv[4] = {};
  #pragma unroll
  for (int k0 = 0; k0 < 192; k0 += 32) {
    short8 pa[4];
    #pragma unroll
    for (int mi = 0; mi < 4; ++mi) pa[mi] = *(const short8*)&Wsh[mi * 16 + fr][k0 + fc];
    short8 vb = *(const short8*)&Vt[wid * 16 + fr][k0 + fc];
    #pragma unroll
    for (int mi = 0; mi < 4; ++mi)
      pv[mi] = MFMA16(pa[mi], vb, pv[mi]);
  }
  __syncthreads();   // invsum visible

  #pragma unroll
  for (int mi = 0; mi < 4; ++mi)
    #pragma unroll
    for (int r = 0; r < 4; ++r) {
      int row = mi * 16 + fq * 4 + r;
      float inv = invsum[row];
      int col = wid * 16 + fr;
      attn[(size_t)(q0 + row) * ATTD + gh * 64 + col] = f2bf(pv[mi][r] * inv);
    }
}

extern "C" void kernel_launch(void* const* d_in, const int* in_sizes, int n_in,
                              void* d_out, int out_size, void* d_ws, size_t ws_size,
                              hipStream_t stream) {
  const float* x          = (const float*)d_in[0];
  const float* norm_scale = (const float*)d_in[1];
  const float* sinks      = (const float*)d_in[2];
  const float* w_qkv      = (const float*)d_in[3];
  const float* b_qkv      = (const float*)d_in[4];
  const float* w_out      = (const float*)d_in[5];
  const float* b_out      = (const float*)d_in[6];
  float* out = (float*)d_out;

  // workspace:
  //   [0, 21.0MB)     qkv_bf  (2048x5120 bf16, pre-RoPE)
  //   [21.0, 37.8MB)  t_bf (11.8MB, dead after gemm1) overlaid by attn_b (16.8MB)
  //   [37.8, 67.3MB)  wbf (w_qkv_bf 29.5MB, then w_out_bf 23.6MB)
  //   [67.3, 67.9MB)  ctab, stab
  char* ws = (char*)d_ws;
  unsigned short* qkv_bf = (unsigned short*)(ws);
  unsigned short* t_bf   = (unsigned short*)(ws + 20971520);
  unsigned short* attn_b = (unsigned short*)(ws + 20971520);
  unsigned short* wbf    = (unsigned short*)(ws + 20971520 + 16777216);
  float*          ctab   = (float*)(ws + 20971520 + 16777216 + 29491200);
  float*          stab   = ctab + NTOK * 32;

  rope_table_kernel<<<dim3(256), dim3(256), 0, stream>>>(ctab, stab);
  rmsnorm_kernel<<<dim3(NTOK), dim3(256), 0, stream>>>(x, norm_scale, t_bf);
  // w_qkv: 5120x2880 fp32 -> bf16
  cvt_w_kernel<<<dim3(14400), dim3(256), 0, stream>>>(w_qkv, wbf, 3686400L);
  // GEMM1: 2048x5120x2880, tiles 128x320 -> 16x16 = 256 blocks
  gemm8p_kernel<320, false><<<dim3(256), dim3(512), 0, stream>>>(
      t_bf, wbf, b_qkv, nullptr, (void*)qkv_bf, HID, QKVD);
  attn_kernel<<<dim3(32, 64), dim3(256), 0, stream>>>(qkv_bf, sinks, ctab, stab, attn_b);
  // w_out: 2880x4096 fp32 -> bf16
  cvt_w_kernel<<<dim3(11520), dim3(256), 0, stream>>>(w_out, wbf, 2949120L);
  // GEMM2: 2048x2880x4096, tiles 128x192 -> 16x15 = 240 blocks
  gemm8p_kernel<192, true><<<dim3(240), dim3(512), 0, stream>>>(
      attn_b, wbf, b_out, x, (void*)out, ATTD, HID);
}

// Round 11
// 208.313 us; speedup vs baseline: 1.8775x; 1.1079x over previous
//
#include <hip/hip_runtime.h>
#include <hip/hip_bf16.h>
#include <math.h>

typedef __attribute__((ext_vector_type(8))) short short8;
typedef __attribute__((ext_vector_type(4))) float f32x4;

#define NTOK 2048
#define HID  2880
#define QKVD 5120
#define KOFF 4096
#define VOFF 4608
#define ATTD 4096   // N_HEADS*HEAD_DIM

__device__ __forceinline__ unsigned short f2bf(float f) {
  union { float f; unsigned int u; } v; v.f = f;
  unsigned int u = v.u;
  unsigned int r = (u + 0x7FFFu + ((u >> 16) & 1u)) >> 16;
  return (unsigned short)r;
}
__device__ __forceinline__ float bf2f(unsigned short h) {
  union { unsigned int u; float f; } v; v.u = ((unsigned int)h) << 16; return v.f;
}
__device__ __forceinline__ void gload_lds16(const unsigned short* g, unsigned short* l) {
  __builtin_amdgcn_global_load_lds(
      (const __attribute__((address_space(1))) unsigned int*)g,
      (__attribute__((address_space(3))) unsigned int*)l, 16, 0, 0);
}
#define MFMA16(a, b, c) __builtin_amdgcn_mfma_f32_16x16x32_bf16((a), (b), (c), 0, 0, 0)

// ---------------- RoPE cos/sin table (YaRN) ----------------
__global__ void rope_table_kernel(float* __restrict__ ctab, float* __restrict__ stab) {
  int idx = blockIdx.x * 256 + threadIdx.x;
  if (idx >= NTOK * 32) return;
  int pos = idx >> 5, i = idx & 31;
  const double theta = 150000.0;
  const double two_pi = 6.283185307179586476925286766559;
  double freq = pow(theta, (double)i / 32.0);
  double interp = 1.0 / (32.0 * freq);
  double extrap = 1.0 / freq;
  double low  = 32.0 * log(4096.0 / (32.0 * two_pi)) / log(theta);
  double high = 32.0 * log(4096.0 / (1.0  * two_pi)) / log(theta);
  double ramp = ((double)i - low) / (high - low);
  ramp = ramp < 0.0 ? 0.0 : (ramp > 1.0 ? 1.0 : ramp);
  double maskv = 1.0 - ramp;
  double inv = interp * (1.0 - maskv) + extrap * maskv;
  double ang = (double)pos * inv;
  double conc = 0.1 * log(32.0) + 1.0;
  ctab[idx] = (float)(cos(ang) * conc);
  stab[idx] = (float)(sin(ang) * conc);
}

// ---------------- RMSNorm fp32 -> bf16 (vectorized) ----------------
__global__ __launch_bounds__(256) void rmsnorm_kernel(
    const float* __restrict__ x, const float* __restrict__ scale,
    unsigned short* __restrict__ t) {
  int row = blockIdx.x;
  const float4* xr = (const float4*)(x + (size_t)row * HID);
  const float4* sc = (const float4*)scale;
  float ss = 0.f;
  for (int c = threadIdx.x; c < HID / 4; c += 256) {
    float4 v = xr[c];
    ss += v.x * v.x + v.y * v.y + v.z * v.z + v.w * v.w;
  }
  #pragma unroll
  for (int m = 1; m < 64; m <<= 1) ss += __shfl_xor(ss, m);
  __shared__ float red[4];
  if ((threadIdx.x & 63) == 0) red[threadIdx.x >> 6] = ss;
  __syncthreads();
  float tot = red[0] + red[1] + red[2] + red[3];
  float rs = rsqrtf(tot / (float)HID + 1e-5f);
  for (int c = threadIdx.x; c < HID / 4; c += 256) {
    float4 v = xr[c];
    float4 s4 = sc[c];
    ushort4 o;
    o.x = f2bf(v.x * rs * s4.x); o.y = f2bf(v.y * rs * s4.y);
    o.z = f2bf(v.z * rs * s4.z); o.w = f2bf(v.w * rs * s4.w);
    *(ushort4*)&t[(size_t)row * HID + c * 4] = o;
  }
}

// ---------------- Weight fp32 -> bf16 ----------------
__global__ __launch_bounds__(256) void cvt_w_kernel(
    const float* __restrict__ w, unsigned short* __restrict__ wb, long total4) {
  long idx = (long)blockIdx.x * 256 + threadIdx.x;
  if (idx >= total4) return;
  long base = idx * 4;
  float4 v = *(const float4*)&w[base];
  ushort4 o;
  o.x = f2bf(v.x); o.y = f2bf(v.y); o.z = f2bf(v.z); o.w = f2bf(v.w);
  *(ushort4*)&wb[base] = o;
}

// ---------------- Pipelined GEMM, 2 blocks/CU (cross-block overlap) ----------
// C[M,NC] = A[M,K]bf16 @ B[NC,K]bf16^T (+bias, +resid)
// BM=128, BN in {160,96}; BK=64; 256 thr = 4 waves (2M x 2N); dbuf LDS,
// 3-bit T2 swizzle; per tile: issue (4+NF) loads -> vmcnt(4+NF) -> barrier ->
// [all ds_reads, then MFMAs] -> barrier. LDS 72/56 KB -> 2 blocks/CU so
// barrier bubbles of one block are covered by the other (m97/m114 mechanism).
template<int BN, bool RESID>
__global__ __launch_bounds__(256, 2) void gemm_kernel(
    const unsigned short* __restrict__ A, const unsigned short* __restrict__ B,
    const float* __restrict__ bias, const float* __restrict__ resid,
    void* __restrict__ Cout, int K, int NC) {
  constexpr int NF = BN / 32;         // per-wave N frags == B staging calls (5 or 3)
  __shared__ unsigned short sA[2][8192];       // 128x64 bf16 per buf (16KB)
  __shared__ unsigned short sB[2][BN * 64];    // BNx64 bf16 per buf

  const int tid = threadIdx.x;
  // XCD-aware swizzle (grid % 8 == 0 for both launches)
  const int q8 = gridDim.x >> 3;
  const int sw = ((int)blockIdx.x & 7) * q8 + ((int)blockIdx.x >> 3);
  const int m0 = (sw & 15) * 128;
  const int n0 = (sw >> 4) * BN;

  const int lane = tid & 63, wid = tid >> 6;   // 4 waves
  const int fr = lane & 15, fq = lane >> 4;
  const int wr = wid >> 1, wc = wid & 1;       // 2M x 2N
  const int swz = (fr & 7) << 4;               // read-side XOR (byte bits 4,5,6)
  const int r_st = tid >> 3;                   // staged row within 32-row call
  const int c8_st = ((tid & 7) ^ ((tid >> 3) & 7)) * 8;  // inverse-swizzled source chunk
  const int wlds = wid << 9;                   // wave's 1KB chunk (ushort units)

  const unsigned short* Ag = A + (size_t)(m0 + r_st) * K + c8_st;
  const unsigned short* Bg = B + (size_t)(n0 + r_st) * K + c8_st;

  f32x4 acc[4][NF] = {};
  const int NT = K >> 6;

  auto LDA_ = [&](int bs, int mf, int ks) -> short8 {
    int row = wr * 64 + mf * 16 + fr;                // row&7 == fr&7
    int cb = (ks * 64 + fq * 16) ^ swz;
    return *(const short8*)((const char*)&sA[bs][0] + row * 128 + cb);
  };
  auto LDB_ = [&](int bs, int nf, int ks) -> short8 {
    int row = wc * (NF * 16) + nf * 16 + fr;         // 80/48 ≡ 0 mod 8 -> row&7==fr&7
    int cb = (ks * 64 + fq * 16) ^ swz;
    return *(const short8*)((const char*)&sB[bs][0] + row * 128 + cb);
  };
  auto issue_tile = [&](int tt, int b) {
    const unsigned short* Agt = Ag + (size_t)tt * 64;
    const unsigned short* Bgt = Bg + (size_t)tt * 64;
    #pragma unroll
    for (int s = 0; s < 4; ++s)                      // A: 4 calls x 32 rows
      gload_lds16(Agt + (size_t)(s * 32) * K, &sA[b][s * 2048 + wlds]);
    #pragma unroll
    for (int s = 0; s < NF; ++s)                     // B: NF calls x 32 rows
      gload_lds16(Bgt + (size_t)(s * 32) * K, &sB[b][s * 2048 + wlds]);
  };

  // -------- prologue: issue tile 0 into buf 0 (no wait yet)
  issue_tile(0, 0);

  for (int t = 0; t < NT; ++t) {
    const int cu = t & 1;
    // ---- issue tile t+1, then ONE counted wait (completes tile t's loads,
    //      leaves tile t+1's (4+NF) in flight with a full tile of slack).
    if (t + 1 < NT) {
      issue_tile(t + 1, cu ^ 1);
      if constexpr (NF == 5) asm volatile("s_waitcnt vmcnt(9)" ::: "memory");
      else                   asm volatile("s_waitcnt vmcnt(7)" ::: "memory");
    } else {
      asm volatile("s_waitcnt vmcnt(0)" ::: "memory");
    }
    __builtin_amdgcn_s_barrier();          // all waves' tile-t loads complete
    __builtin_amdgcn_sched_barrier(0);     // keep ds_reads below readiness point
    // ---- preload ALL fragments for the tile (both ks halves), then MFMA
    short8 afr0[4], bfr0[NF], afr1[4], bfr1[NF];
    #pragma unroll
    for (int mf = 0; mf < 4; ++mf) afr0[mf] = LDA_(cu, mf, 0);
    #pragma unroll
    for (int nf = 0; nf < NF; ++nf) bfr0[nf] = LDB_(cu, nf, 0);
    #pragma unroll
    for (int mf = 0; mf < 4; ++mf) afr1[mf] = LDA_(cu, mf, 1);
    #pragma unroll
    for (int nf = 0; nf < NF; ++nf) bfr1[nf] = LDB_(cu, nf, 1);
    __builtin_amdgcn_s_setprio(1);
    #pragma unroll
    for (int mf = 0; mf < 4; ++mf)
      #pragma unroll
      for (int nf = 0; nf < NF; ++nf)
        acc[mf][nf] = MFMA16(afr0[mf], bfr0[nf], acc[mf][nf]);
    #pragma unroll
    for (int mf = 0; mf < 4; ++mf)
      #pragma unroll
      for (int nf = 0; nf < NF; ++nf)
        acc[mf][nf] = MFMA16(afr1[mf], bfr1[nf], acc[mf][nf]);
    __builtin_amdgcn_s_setprio(0);
    // ---- end of tile: reads from buf cu done -> next iter may stage into it
    __builtin_amdgcn_s_barrier();
  }

  // -------- epilogue
  if (!RESID) {
    unsigned short* C = (unsigned short*)Cout;
    #pragma unroll
    for (int mf = 0; mf < 4; ++mf)
      #pragma unroll
      for (int nf = 0; nf < NF; ++nf)
        #pragma unroll
        for (int r = 0; r < 4; ++r) {
          int row = m0 + wr * 64 + mf * 16 + fq * 4 + r;
          int col = n0 + wc * (NF * 16) + nf * 16 + fr;
          C[(size_t)row * NC + col] = f2bf(acc[mf][nf][r] + bias[col]);
        }
  } else {
    float* C = (float*)Cout;
    #pragma unroll
    for (int mf = 0; mf < 4; ++mf)
      #pragma unroll
      for (int nf = 0; nf < NF; ++nf)
        #pragma unroll
        for (int r = 0; r < 4; ++r) {
          int row = m0 + wr * 64 + mf * 16 + fq * 4 + r;
          int col = n0 + wc * (NF * 16) + nf * 16 + fr;
          C[(size_t)row * NC + col] = acc[mf][nf][r] + bias[col] + resid[(size_t)row * NC + col];
        }
  }
}

// ---------------- MFMA sliding-window attention with sinks + fused RoPE ----------------
__global__ __launch_bounds__(256) void attn_kernel(
    const unsigned short* __restrict__ qkv, const float* __restrict__ sinks,
    const float* __restrict__ ctab, const float* __restrict__ stab,
    unsigned short* __restrict__ attn) {
  const int tile = blockIdx.x;
  const int gh = blockIdx.y;
  const int h = gh >> 3;
  const int q0 = tile * 64;
  const int kbase = q0 - 127;

  __shared__ unsigned short Qsh[64][72];
  __shared__ unsigned short Ksh[192][72];
  __shared__ unsigned short Vt[64][200];    // transposed V: [dim][key]
  __shared__ float rowpart[4][64];
  __shared__ float invsum[64];
  unsigned short (*Wsh)[200] = (unsigned short (*)[200])Ksh;  // overlay after scores

  const int tid = threadIdx.x;

  // ---- stage Q with RoPE
  {
    int r = tid >> 2, cp = tid & 3;
    int i = q0 + r;
    const unsigned short* qp = &qkv[(size_t)i * QKVD + gh * 64 + cp * 8];
    short8 xa = *(const short8*)qp;
    short8 xb = *(const short8*)(qp + 32);
    short8 oa, ob;
    #pragma unroll
    for (int e = 0; e < 8; ++e) {
      float c = ctab[i * 32 + cp * 8 + e], s = stab[i * 32 + cp * 8 + e];
      float x1 = bf2f((unsigned short)xa[e]), x2 = bf2f((unsigned short)xb[e]);
      oa[e] = (short)f2bf(x1 * c - x2 * s);
      ob[e] = (short)f2bf(x2 * c + x1 * s);
    }
    *(short8*)&Qsh[r][cp * 8] = oa;
    *(short8*)&Qsh[r][cp * 8 + 32] = ob;
  }
  // ---- stage K with RoPE, zero-fill out-of-range
  #pragma unroll
  for (int it = 0; it < 3; ++it) {
    int lin = tid + it * 256;
    int r = lin >> 2, cp = lin & 3;
    int j = kbase + r;
    short8 oa = {}, ob = {};
    if (j >= 0 && j < NTOK) {
      const unsigned short* kp = &qkv[(size_t)j * QKVD + KOFF + h * 64 + cp * 8];
      short8 xa = *(const short8*)kp;
      short8 xb = *(const short8*)(kp + 32);
      #pragma unroll
      for (int e = 0; e < 8; ++e) {
        float c = ctab[j * 32 + cp * 8 + e], s = stab[j * 32 + cp * 8 + e];
        float x1 = bf2f((unsigned short)xa[e]), x2 = bf2f((unsigned short)xb[e]);
        oa[e] = (short)f2bf(x1 * c - x2 * s);
        ob[e] = (short)f2bf(x2 * c + x1 * s);
      }
    }
    *(short8*)&Ksh[r][cp * 8] = oa;
    *(short8*)&Ksh[r][cp * 8 + 32] = ob;
  }
  // ---- stage V transposed
  #pragma unroll
  for (int c = 0; c < 6; ++c) {
    int lin = tid + c * 256;
    int r = lin >> 3, ch = (lin & 7) * 8;
    int j = kbase + r;
    uint4 v = make_uint4(0u, 0u, 0u, 0u);
    if (j >= 0 && j < NTOK) v = *(const uint4*)&qkv[(size_t)j * QKVD + VOFF + h * 64 + ch];
    const unsigned short* vs = (const unsigned short*)&v;
    #pragma unroll
    for (int i2 = 0; i2 < 8; ++i2) Vt[ch + i2][r] = vs[i2];
  }
  __syncthreads();

  const int lane = tid & 63;
  const int wid = tid >> 6;
  const int fr = lane & 15;
  const int fq = lane >> 4;
  const int fc = fq * 8;
  const int wk0 = wid * 48;

  // ---- scores: S[64][48] per wave
  f32x4 sc[4][3] = {};
  #pragma unroll
  for (int k0 = 0; k0 < 64; k0 += 32) {
    short8 qa[4], kb[3];
    #pragma unroll
    for (int mi = 0; mi < 4; ++mi) qa[mi] = *(const short8*)&Qsh[mi * 16 + fr][k0 + fc];
    #pragma unroll
    for (int ni = 0; ni < 3; ++ni) kb[ni] = *(const short8*)&Ksh[wk0 + ni * 16 + fr][k0 + fc];
    #pragma unroll
    for (int mi = 0; mi < 4; ++mi)
      #pragma unroll
      for (int ni = 0; ni < 3; ++ni)
        sc[mi][ni] = MFMA16(qa[mi], kb[ni], sc[mi][ni]);
  }

  // ---- mask + exp in-register; per-row partial sums
  float rsum[4][4];
  #pragma unroll
  for (int mi = 0; mi < 4; ++mi)
    #pragma unroll
    for (int r = 0; r < 4; ++r) {
      int i = q0 + mi * 16 + fq * 4 + r;
      float rs = 0.f;
      #pragma unroll
      for (int ni = 0; ni < 3; ++ni) {
        int kk = wk0 + ni * 16 + fr;
        int j = kbase + kk;
        bool valid = (j >= 0) && (j <= i) && (j > i - 128);
        float pw = valid ? __expf(sc[mi][ni][r] * 0.125f) : 0.f;
        sc[mi][ni][r] = pw;
        rs += pw;
      }
      rs += __shfl_xor(rs, 1);
      rs += __shfl_xor(rs, 2);
      rs += __shfl_xor(rs, 4);
      rs += __shfl_xor(rs, 8);
      rsum[mi][r] = rs;
    }

  __syncthreads();   // all Ksh reads complete; safe to overlay Wsh

  #pragma unroll
  for (int mi = 0; mi < 4; ++mi)
    #pragma unroll
    for (int r = 0; r < 4; ++r) {
      int row = mi * 16 + fq * 4 + r;
      #pragma unroll
      for (int ni = 0; ni < 3; ++ni)
        Wsh[row][wk0 + ni * 16 + fr] = f2bf(sc[mi][ni][r]);
      if (fr == 0) rowpart[wid][row] = rsum[mi][r];
    }
  __syncthreads();

  if (tid < 64) {
    float tot = rowpart[0][tid] + rowpart[1][tid] + rowpart[2][tid] + rowpart[3][tid];
    invsum[tid] = 1.f / (tot + __expf(sinks[gh]));
  }

  // ---- PV: out[64][16] per wave, K=192
  f32x4 pv[4] = {};
  #pragma unroll
  for (int k0 = 0; k0 < 192; k0 += 32) {
    short8 pa[4];
    #pragma unroll
    for (int mi = 0; mi < 4; ++mi) pa[mi] = *(const short8*)&Wsh[mi * 16 + fr][k0 + fc];
    short8 vb = *(const short8*)&Vt[wid * 16 + fr][k0 + fc];
    #pragma unroll
    for (int mi = 0; mi < 4; ++mi)
      pv[mi] = MFMA16(pa[mi], vb, pv[mi]);
  }
  __syncthreads();   // invsum visible

  #pragma unroll
  for (int mi = 0; mi < 4; ++mi)
    #pragma unroll
    for (int r = 0; r < 4; ++r) {
      int row = mi * 16 + fq * 4 + r;
      float inv = invsum[row];
      int col = wid * 16 + fr;
      attn[(size_t)(q0 + row) * ATTD + gh * 64 + col] = f2bf(pv[mi][r] * inv);
    }
}

extern "C" void kernel_launch(void* const* d_in, const int* in_sizes, int n_in,
                              void* d_out, int out_size, void* d_ws, size_t ws_size,
                              hipStream_t stream) {
  const float* x          = (const float*)d_in[0];
  const float* norm_scale = (const float*)d_in[1];
  const float* sinks      = (const float*)d_in[2];
  const float* w_qkv      = (const float*)d_in[3];
  const float* b_qkv      = (const float*)d_in[4];
  const float* w_out      = (const float*)d_in[5];
  const float* b_out      = (const float*)d_in[6];
  float* out = (float*)d_out;

  // workspace:
  //   [0, 21.0MB)     qkv_bf  (2048x5120 bf16, pre-RoPE)
  //   [21.0, 37.8MB)  t_bf (11.8MB, dead after gemm1) overlaid by attn_b (16.8MB)
  //   [37.8, 67.3MB)  wbf (w_qkv_bf 29.5MB, then w_out_bf 23.6MB)
  //   [67.3, 67.9MB)  ctab, stab
  char* ws = (char*)d_ws;
  unsigned short* qkv_bf = (unsigned short*)(ws);
  unsigned short* t_bf   = (unsigned short*)(ws + 20971520);
  unsigned short* attn_b = (unsigned short*)(ws + 20971520);
  unsigned short* wbf    = (unsigned short*)(ws + 20971520 + 16777216);
  float*          ctab   = (float*)(ws + 20971520 + 16777216 + 29491200);
  float*          stab   = ctab + NTOK * 32;

  rope_table_kernel<<<dim3(256), dim3(256), 0, stream>>>(ctab, stab);
  rmsnorm_kernel<<<dim3(NTOK), dim3(256), 0, stream>>>(x, norm_scale, t_bf);
  // w_qkv: 5120x2880 fp32 -> bf16
  cvt_w_kernel<<<dim3(14400), dim3(256), 0, stream>>>(w_qkv, wbf, 3686400L);
  // GEMM1: 2048x5120x2880, tiles 128x160 -> 16x32 = 512 blocks (2/CU)
  gemm_kernel<160, false><<<dim3(512), dim3(256), 0, stream>>>(
      t_bf, wbf, b_qkv, nullptr, (void*)qkv_bf, HID, QKVD);
  attn_kernel<<<dim3(32, 64), dim3(256), 0, stream>>>(qkv_bf, sinks, ctab, stab, attn_b);
  // w_out: 2880x4096 fp32 -> bf16
  cvt_w_kernel<<<dim3(11520), dim3(256), 0, stream>>>(w_out, wbf, 2949120L);
  // GEMM2: 2048x2880x4096, tiles 128x96 -> 16x30 = 480 blocks (2/CU)
  gemm_kernel<96, true><<<dim3(480), dim3(256), 0, stream>>>(
      attn_b, wbf, b_out, x, (void*)out, ATTD, HID);
}